// Round 7
// baseline (513.810 us; speedup 1.0000x reference)
//
#include <hip/hip_runtime.h>
#include <math.h>

// Problem constants (B=2, H=16, S=2048, K=V=128, CHUNK=64)
#define CDIM 128
#define LCH  64
#define NCHK 32
#define NBH  32
#define SEQ  2048
#define NCHUNKS 1024
#define SCALE 0.08838834764831845f

typedef unsigned short u16;
typedef unsigned int   u32;

__device__ __forceinline__ u16 f2bf(float f) {
    u32 u;
    __builtin_memcpy(&u, &f, 4);
    u32 r = u + 0x7fffu + ((u >> 16) & 1u);   // round-to-nearest-even
    return (u16)(r >> 16);
}
__device__ __forceinline__ float bf2f_bits(u32 low16) {
    u32 u = low16 << 16;
    float f;
    __builtin_memcpy(&f, &u, 4);
    return f;
}

// ---------- probe kernel (execution witness; template-named) ----------
extern "C" __global__ __launch_bounds__(256)
void KDABlock_4475355922517_kernel(float* out, int n, float val)
{
    int stride = gridDim.x * blockDim.x;
    for (int i = blockIdx.x * blockDim.x + threadIdx.x; i < n; i += stride)
        out[i] = val;
}

// ---------- Phase A1: per-chunk local quantities (1024 blocks, parallel) ----------
// CORRECTED: rel[i,j,k] = exp(gcum[j,k] - gcum[i,k])  =>
//   kk = klo @ khi^T   (klo = kn*e^{-gcum}, khi = kn*e^{+gcum})
//   qk = qlo @ khi^T   (qlo = qn*e^{-gcum})
// Stores: khi (64x128 bf16), Qn = scale*e^gcm*qn (64x128 bf16), T (64x64 f32),
//         qk_masked (64x64 f32), egt (128 f32), egcm (64 f32).
extern "C" __global__ __launch_bounds__(512)
void kda_phaseA1(const float* gq, const float* gk, const float* gg, const float* gbeta,
                 u16* wkhi, u16* wqn, float* wT, float* wqk, float* wegt, float* wegcm)
{
    __shared__ float arena[8704];   // 34,816 B
    __shared__ float sbeta[64];

    const int chunk = blockIdx.x;
    const int bh = chunk >> 5, tt = chunk & 31;
    const int tid = threadIdx.x;
    const int base = bh * (SEQ * CDIM) + tt * (LCH * CDIM);
    const int row = tid >> 3, part = tid & 7;

    // gcum: segmented cumsum over 64 rows per column (arena stride 130)
    {
        const int col = tid & 127, seg = tid >> 7;
        float acc = 0.f;
        for (int r = 0; r < 16; ++r) {
            const int i = seg * 16 + r;
            acc += gg[base + i * CDIM + col];
            arena[i * 130 + col] = acc;
        }
        __syncthreads();
        float off = 0.f;
        for (int s = 0; s < seg; ++s) off += arena[(s * 16 + 15) * 130 + col];
        __syncthreads();
        if (seg) {
            for (int r = 0; r < 16; ++r) arena[(seg * 16 + r) * 130 + col] += off;
        }
        if (tid < 64) sbeta[tid] = gbeta[bh * SEQ + tt * LCH + tid];
    }
    __syncthreads();

    // gcum -> registers; egt; egcm
    float gc[16];
    #pragma unroll
    for (int c = 0; c < 16; ++c) gc[c] = arena[row * 130 + part * 16 + c];
    if (tid < 128) wegt[chunk * CDIM + tid] = __expf(arena[63 * 130 + tid]);
    float egr;
    {
        float s = 0.f;
        #pragma unroll
        for (int c = 0; c < 16; ++c) s += gc[c];
        s += __shfl_xor(s, 1); s += __shfl_xor(s, 2); s += __shfl_xor(s, 4);
        egr = __expf(s * (1.f / 128.f));
        if (part == 0) wegcm[chunk * LCH + row] = egr;
    }

    // k: normalize -> khi/klo regs; khi -> ws (bf16)
    float khi[16], klo[16];
    {
        float ss = 0.f;
        const float* kp = gk + base + row * CDIM + part * 16;
        #pragma unroll
        for (int c = 0; c < 16; ++c) { khi[c] = kp[c]; ss += khi[c] * khi[c]; }
        ss += __shfl_xor(ss, 1); ss += __shfl_xor(ss, 2); ss += __shfl_xor(ss, 4);
        const float inv = 1.f / (sqrtf(ss) + 1e-6f);
        #pragma unroll
        for (int c = 0; c < 16; ++c) {
            const float kn = khi[c] * inv;
            khi[c] = kn * __expf(gc[c]);
            klo[c] = kn * __expf(-gc[c]);
            wkhi[chunk * 8192 + row * CDIM + part * 16 + c] = f2bf(khi[c]);
        }
    }

    // q: normalize -> qlo regs; Qn -> ws (bf16)
    float qlo[16];
    {
        float ss = 0.f;
        const float* qp = gq + base + row * CDIM + part * 16;
        #pragma unroll
        for (int c = 0; c < 16; ++c) { qlo[c] = qp[c]; ss += qlo[c] * qlo[c]; }
        ss += __shfl_xor(ss, 1); ss += __shfl_xor(ss, 2); ss += __shfl_xor(ss, 4);
        const float inv = 1.f / (sqrtf(ss) + 1e-6f);
        const float qs = SCALE * egr * inv;
        #pragma unroll
        for (int c = 0; c < 16; ++c) {
            wqn[chunk * 8192 + row * CDIM + part * 16 + c] = f2bf(qlo[c] * qs);
            qlo[c] = qlo[c] * inv * __expf(-gc[c]);
        }
    }
    __syncthreads();   // gcum readers done; arena reused

    // stage khi^T: arena[k*68 + j] = khi[j][k]
    #pragma unroll
    for (int c = 0; c < 16; ++c) arena[(part * 16 + c) * 68 + row] = khi[c];
    __syncthreads();

    // kk = klo@khi^T, qk = qlo@khi^T (klo/qlo row values via shfl broadcast)
    float rk[8], rq[8];
    #pragma unroll
    for (int d = 0; d < 8; ++d) { rk[d] = 0.f; rq[d] = 0.f; }
    const int j0 = part * 8;
    const int lb8 = (row & 7) << 3;
    for (int kb = 0; kb < 8; ++kb) {
        #pragma unroll
        for (int kc = 0; kc < 16; ++kc) {
            const int k2 = kb * 16 + kc;
            const float a = __shfl(klo[kc], lb8 + kb);
            const float b = __shfl(qlo[kc], lb8 + kb);
            const float* hp = &arena[k2 * 68 + j0];
            #pragma unroll
            for (int d = 0; d < 8; ++d) { rk[d] += a * hp[d]; rq[d] += b * hp[d]; }
        }
    }

    // qk_masked -> ws
    #pragma unroll
    for (int d = 0; d < 8; ++d) {
        const int j = j0 + d;
        wqk[chunk * 4096 + row * 64 + j] = (j <= row) ? rq[d] * SCALE : 0.f;
    }
    __syncthreads();   // khi^T reads done; arena reused for tkk/tT

    #pragma unroll
    for (int d = 0; d < 8; ++d) arena[row * 68 + j0 + d] = rk[d];
    __syncthreads();

    // T solve: (I + beta_i*strict_lower(kk)) T = diag(beta); lane j owns column j
    if (tid < 64) {
        const int j = tid;
        for (int i = 0; i < LCH; ++i) {
            float s = 0.f;
            for (int m = 0; m < i; ++m)
                s += arena[i * 68 + m] * arena[4352 + m * 68 + j];
            arena[4352 + i * 68 + j] = sbeta[i] * (((j == i) ? 1.f : 0.f) - s);
        }
    }
    __syncthreads();

    // T -> ws
    #pragma unroll
    for (int d = 0; d < 8; ++d)
        wT[chunk * 4096 + row * 64 + j0 + d] = arena[4352 + row * 68 + j0 + d];
}

// ---------- Phase A2: G = qk_masked @ T (in place over wqk) ----------
extern "C" __global__ __launch_bounds__(512)
void kda_phaseA2(float* wqkG, const float* wT)
{
    __shared__ float tqk[4352];   // 64 x 68
    __shared__ float tTl[4352];
    const int chunk = blockIdx.x, tid = threadIdx.x;
    const int row = tid >> 3, cc = (tid & 7) * 8;
    #pragma unroll
    for (int d = 0; d < 8; ++d) {
        tqk[row * 68 + cc + d] = wqkG[chunk * 4096 + row * 64 + cc + d];
        tTl[row * 68 + cc + d] = wT[chunk * 4096 + row * 64 + cc + d];
    }
    __syncthreads();
    float g[8];
    #pragma unroll
    for (int d = 0; d < 8; ++d) g[d] = 0.f;
    for (int m = 0; m < LCH; ++m) {
        const float a = tqk[row * 68 + m];
        const float* tp = &tTl[m * 68 + cc];
        #pragma unroll
        for (int d = 0; d < 8; ++d) g[d] += a * tp[d];
    }
    __syncthreads();
    #pragma unroll
    for (int d = 0; d < 8; ++d) wqkG[chunk * 4096 + row * 64 + cc + d] = g[d];
}

// ---------- Phase B: sequential scan; 32 chains x 8 column-groups of 16 ----------
// pass1: X = vg - khi@S ; O = Qn@S    pass2: corr = T@X ; O += G@X ; write O
// pass3: S = diag(egt)S + khi^T@corr
extern "C" __global__ __launch_bounds__(512)
void kda_phaseB(const u16* wkhi, const u16* wqn, const float* wT, const float* wG,
                const float* wegt, const float* wegcm, const float* gv, float* gout)
{
    __shared__ u32 sKhi[LCH][64];   // word j holds bf16 cols 2j, 2j+1
    __shared__ u32 sQn [LCH][64];
    __shared__ float sS[CDIM][18];
    __shared__ float sX[LCH][18];
    __shared__ float sC[LCH][18];

    const int bh = blockIdx.x >> 3;
    const int c0 = (blockIdx.x & 7) * 16;
    const int tid = threadIdx.x;
    const int row = tid >> 3, p = tid & 7;
    const int kx = tid >> 2, qq = tid & 3;
    const int lb8 = (row & 7) << 3;

    for (int e = tid; e < CDIM * 16; e += 512) sS[e >> 4][e & 15] = 0.f;
    __syncthreads();

    float* outO = gout + bh * (SEQ * CDIM);
    float* outS = gout + NBH * (SEQ * CDIM) + bh * (CDIM * CDIM);

    for (int t = 0; t < NCHK; ++t) {
        const int chunk = bh * NCHK + t;

        float tRa[8], gRa[8];
        {
            const u16* ks = wkhi + chunk * 8192 + row * CDIM + p * 16;
            const u16* qs = wqn  + chunk * 8192 + row * CDIM + p * 16;
            #pragma unroll
            for (int d = 0; d < 8; ++d) {
                sKhi[row][p * 8 + d] = (u32)ks[2 * d] | ((u32)ks[2 * d + 1] << 16);
                sQn [row][p * 8 + d] = (u32)qs[2 * d] | ((u32)qs[2 * d + 1] << 16);
            }
            const float* tp = wT + chunk * 4096 + row * 64 + p * 8;
            const float* gp = wG + chunk * 4096 + row * 64 + p * 8;
            #pragma unroll
            for (int d = 0; d < 8; ++d) { tRa[d] = tp[d]; gRa[d] = gp[d]; }
            const float em = wegcm[chunk * LCH + row];
            const float* vp = gv + bh * (SEQ * CDIM) + (t * LCH + row) * CDIM + c0;
            sX[row][2 * p]     = vp[2 * p] * em;
            sX[row][2 * p + 1] = vp[2 * p + 1] * em;
        }
        const float et = wegt[chunk * CDIM + kx];
        __syncthreads();

        // pass1
        float x0 = sX[row][2 * p], x1 = sX[row][2 * p + 1];
        float o0 = 0.f, o1 = 0.f;
        for (int u = 0; u < 64; ++u) {
            const u32 ku = sKhi[row][u];
            const u32 qu = sQn[row][u];
            const float ka = bf2f_bits(ku & 0xffffu), kb = bf2f_bits(ku >> 16);
            const float qa = bf2f_bits(qu & 0xffffu), qb = bf2f_bits(qu >> 16);
            const float s0a = sS[2 * u][2 * p],     s0b = sS[2 * u][2 * p + 1];
            const float s1a = sS[2 * u + 1][2 * p], s1b = sS[2 * u + 1][2 * p + 1];
            x0 -= ka * s0a; x1 -= ka * s0b;
            x0 -= kb * s1a; x1 -= kb * s1b;
            o0 += qa * s0a; o1 += qa * s0b;
            o0 += qb * s1a; o1 += qb * s1b;
        }
        sX[row][2 * p] = x0; sX[row][2 * p + 1] = x1;
        __syncthreads();

        // pass2
        {
            float ra = 0.f, rb = 0.f;
            for (int mb = 0; mb < 8; ++mb) {
                #pragma unroll
                for (int d = 0; d < 8; ++d) {
                    const int m = mb * 8 + d;
                    const float tv = __shfl(tRa[d], lb8 + mb);
                    const float gw = __shfl(gRa[d], lb8 + mb);
                    const float xa = sX[m][2 * p], xb = sX[m][2 * p + 1];
                    ra += tv * xa; rb += tv * xb;
                    o0 += gw * xa; o1 += gw * xb;
                }
            }
            sC[row][2 * p] = ra; sC[row][2 * p + 1] = rb;
            outO[(t * LCH + row) * CDIM + c0 + 2 * p]     = o0;
            outO[(t * LCH + row) * CDIM + c0 + 2 * p + 1] = o1;
        }
        __syncthreads();

        // pass3
        {
            float a0 = et * sS[kx][4 * qq];
            float a1 = et * sS[kx][4 * qq + 1];
            float a2 = et * sS[kx][4 * qq + 2];
            float a3 = et * sS[kx][4 * qq + 3];
            const int kw = kx >> 1, ksh = (kx & 1) * 16;
            for (int i = 0; i < LCH; ++i) {
                const float kv = bf2f_bits((sKhi[i][kw] >> ksh) & 0xffffu);
                a0 += kv * sC[i][4 * qq];
                a1 += kv * sC[i][4 * qq + 1];
                a2 += kv * sC[i][4 * qq + 2];
                a3 += kv * sC[i][4 * qq + 3];
            }
            sS[kx][4 * qq]     = a0;
            sS[kx][4 * qq + 1] = a1;
            sS[kx][4 * qq + 2] = a2;
            sS[kx][4 * qq + 3] = a3;
        }
        __syncthreads();
    }

    for (int d = 0; d < 4; ++d)
        outS[kx * CDIM + c0 + 4 * qq + d] = sS[kx][4 * qq + d];
}

extern "C" __attribute__((visibility("default")))
void kernel_launch(void* const* d_in, const int* in_sizes, int n_in,
                   void* d_out, int out_size, void* d_ws, size_t ws_size,
                   hipStream_t stream)
{
    const size_t safe_bytes = (size_t)out_size * 2;  // safe under f32 or bf16 buffer

    // --- stream validity guard (capture-safe order) ---
    hipStream_t s = stream;
    hipStreamCaptureStatus cs = hipStreamCaptureStatusNone;
    (void)hipStreamIsCapturing(stream, &cs);
    if (cs == hipStreamCaptureStatusNone) {
        hipError_t qe = hipStreamQuery(stream);
        if (qe != hipSuccess && qe != hipErrorNotReady) s = (hipStream_t)0;
    }

    // Marker A (kernel-free): kernel_launch ran. 0x4C -> absmax ~5.3e7 if nothing else lands.
    (void)hipMemsetAsync(d_out, 0x4C, safe_bytes, s);

    const bool sizes_ok = (n_in >= 5)
        && in_sizes[0] == 8388608 && in_sizes[1] == 8388608
        && in_sizes[2] == 8388608 && in_sizes[3] == 8388608
        && in_sizes[4] == 65536 && out_size == 8912896;
    if (!sizes_ok) {   // 0x5A -> ~1.5e16
        (void)hipMemsetAsync(d_out, 0x5A, safe_bytes, s);
        return;
    }
    const size_t NEED = (size_t)NCHUNKS * 8192 * 2 * 2
                      + (size_t)NCHUNKS * 4096 * 4 * 2
                      + (size_t)NCHUNKS * (CDIM + LCH) * 4;
    if (d_ws == 0 || ws_size < NEED) {   // 0x56 -> ~5.9e13
        (void)hipMemsetAsync(d_out, 0x56, safe_bytes, s);
        return;
    }

    // Marker B: kernels execute (1e9 fill over a region the pipeline overwrites).
    (void)hipGetLastError();
    KDABlock_4475355922517_kernel<<<1024, 256, 0, s>>>((float*)d_out, out_size / 2, 1.0e9f);

    const float* q    = (const float*)d_in[0];
    const float* k    = (const float*)d_in[1];
    const float* v    = (const float*)d_in[2];
    const float* g    = (const float*)d_in[3];
    const float* beta = (const float*)d_in[4];
    float* out = (float*)d_out;

    u16* wkhi  = (u16*)d_ws;
    u16* wqn   = wkhi + (size_t)NCHUNKS * 8192;
    float* wT  = (float*)(wqn + (size_t)NCHUNKS * 8192);
    float* wqkG = wT + (size_t)NCHUNKS * 4096;
    float* wegt = wqkG + (size_t)NCHUNKS * 4096;
    float* wegcm = wegt + (size_t)NCHUNKS * CDIM;

    kda_phaseA1<<<NCHUNKS, 512, 0, s>>>(q, k, g, beta, wkhi, wqn, wT, wqkG, wegt, wegcm);
    kda_phaseA2<<<NCHUNKS, 512, 0, s>>>(wqkG, wT);
    kda_phaseB<<<NBH * 8, 512, 0, s>>>(wkhi, wqn, wT, wqkG, wegt, wegcm, v, out);

    if (hipGetLastError() != hipSuccess) {   // 0x66 -> ~2.7e23 : a launch was rejected
        (void)hipMemsetAsync(d_out, 0x66, safe_bytes, s);
    }
}

// Round 8
// 402.252 us; speedup vs baseline: 1.2773x; 1.2773x over previous
//
#include <hip/hip_runtime.h>
#include <math.h>

// Problem constants (B=2, H=16, S=2048, K=V=128, CHUNK=64)
#define CDIM 128
#define LCH  64
#define NCHK 32
#define NBH  32
#define SEQ  2048
#define NCHUNKS 1024
#define SCALE 0.08838834764831845f

typedef unsigned short u16;
typedef unsigned int   u32;

__device__ __forceinline__ u16 f2bf(float f) {
    u32 u;
    __builtin_memcpy(&u, &f, 4);
    u32 r = u + 0x7fffu + ((u >> 16) & 1u);   // round-to-nearest-even
    return (u16)(r >> 16);
}
__device__ __forceinline__ float bf2f_bits(u32 low16) {
    u32 u = low16 << 16;
    float f;
    __builtin_memcpy(&f, &u, 4);
    return f;
}

// ---------- kept for symbol compatibility (not launched) ----------
extern "C" __global__ __launch_bounds__(256)
void KDABlock_4475355922517_kernel(float* out, int n, float val)
{
    int stride = gridDim.x * blockDim.x;
    for (int i = blockIdx.x * blockDim.x + threadIdx.x; i < n; i += stride)
        out[i] = val;
}

// ---------- Phase A1: per-chunk local quantities + fused G (1024 blocks) ----------
//   kk = klo @ khi^T   (klo = kn*e^{-gcum}, khi = kn*e^{+gcum})
//   qk = qlo @ khi^T ; T solve ; G = qk_masked @ T  (fused, qk held in regs)
// Stores: khi (64x128 bf16), Qn (64x128 bf16), T (64x64 f32), G (64x64 f32),
//         egt (128 f32), egcm (64 f32).
extern "C" __global__ __launch_bounds__(512)
void kda_phaseA1(const float* gq, const float* gk, const float* gg, const float* gbeta,
                 u16* wkhi, u16* wqn, float* wT, float* wG, float* wegt, float* wegcm)
{
    __shared__ float arena[8704];   // 34,816 B
    __shared__ float sbeta[64];

    const int chunk = blockIdx.x;
    const int bh = chunk >> 5, tt = chunk & 31;
    const int tid = threadIdx.x;
    const int base = bh * (SEQ * CDIM) + tt * (LCH * CDIM);
    const int row = tid >> 3, part = tid & 7;

    // gcum: segmented cumsum over 64 rows per column (arena stride 130)
    {
        const int col = tid & 127, seg = tid >> 7;
        float acc = 0.f;
        for (int r = 0; r < 16; ++r) {
            const int i = seg * 16 + r;
            acc += gg[base + i * CDIM + col];
            arena[i * 130 + col] = acc;
        }
        __syncthreads();
        float off = 0.f;
        for (int s = 0; s < seg; ++s) off += arena[(s * 16 + 15) * 130 + col];
        __syncthreads();
        if (seg) {
            for (int r = 0; r < 16; ++r) arena[(seg * 16 + r) * 130 + col] += off;
        }
        if (tid < 64) sbeta[tid] = gbeta[bh * SEQ + tt * LCH + tid];
    }
    __syncthreads();

    // gcum -> registers; egt; egcm
    float gc[16];
    #pragma unroll
    for (int c = 0; c < 16; ++c) gc[c] = arena[row * 130 + part * 16 + c];
    if (tid < 128) wegt[chunk * CDIM + tid] = __expf(arena[63 * 130 + tid]);
    float egr;
    {
        float s = 0.f;
        #pragma unroll
        for (int c = 0; c < 16; ++c) s += gc[c];
        s += __shfl_xor(s, 1); s += __shfl_xor(s, 2); s += __shfl_xor(s, 4);
        egr = __expf(s * (1.f / 128.f));
        if (part == 0) wegcm[chunk * LCH + row] = egr;
    }

    // k: normalize -> khi/klo regs; khi -> ws (bf16)
    float khi[16], klo[16];
    {
        float ss = 0.f;
        const float* kp = gk + base + row * CDIM + part * 16;
        #pragma unroll
        for (int c = 0; c < 16; ++c) { khi[c] = kp[c]; ss += khi[c] * khi[c]; }
        ss += __shfl_xor(ss, 1); ss += __shfl_xor(ss, 2); ss += __shfl_xor(ss, 4);
        const float inv = 1.f / (sqrtf(ss) + 1e-6f);
        #pragma unroll
        for (int c = 0; c < 16; ++c) {
            const float kn = khi[c] * inv;
            khi[c] = kn * __expf(gc[c]);
            klo[c] = kn * __expf(-gc[c]);
            wkhi[chunk * 8192 + row * CDIM + part * 16 + c] = f2bf(khi[c]);
        }
    }

    // q: normalize -> qlo regs; Qn -> ws (bf16)
    float qlo[16];
    {
        float ss = 0.f;
        const float* qp = gq + base + row * CDIM + part * 16;
        #pragma unroll
        for (int c = 0; c < 16; ++c) { qlo[c] = qp[c]; ss += qlo[c] * qlo[c]; }
        ss += __shfl_xor(ss, 1); ss += __shfl_xor(ss, 2); ss += __shfl_xor(ss, 4);
        const float inv = 1.f / (sqrtf(ss) + 1e-6f);
        const float qs = SCALE * egr * inv;
        #pragma unroll
        for (int c = 0; c < 16; ++c) {
            wqn[chunk * 8192 + row * CDIM + part * 16 + c] = f2bf(qlo[c] * qs);
            qlo[c] = qlo[c] * inv * __expf(-gc[c]);
        }
    }
    __syncthreads();   // gcum readers done; arena reused

    // stage khi^T: arena[k*68 + j] = khi[j][k]
    #pragma unroll
    for (int c = 0; c < 16; ++c) arena[(part * 16 + c) * 68 + row] = khi[c];
    __syncthreads();

    // kk = klo@khi^T, qk = qlo@khi^T (klo/qlo rows via shfl broadcast)
    float rk[8], rqm[8];
    #pragma unroll
    for (int d = 0; d < 8; ++d) { rk[d] = 0.f; rqm[d] = 0.f; }
    const int j0 = part * 8;
    const int lb8 = (row & 7) << 3;
    for (int kb = 0; kb < 8; ++kb) {
        #pragma unroll
        for (int kc = 0; kc < 16; ++kc) {
            const int k2 = kb * 16 + kc;
            const float a = __shfl(klo[kc], lb8 + kb);
            const float b = __shfl(qlo[kc], lb8 + kb);
            const float* hp = &arena[k2 * 68 + j0];
            #pragma unroll
            for (int d = 0; d < 8; ++d) { rk[d] += a * hp[d]; rqm[d] += b * hp[d]; }
        }
    }
    // mask+scale qk in regs (kept for fused G)
    #pragma unroll
    for (int d = 0; d < 8; ++d) rqm[d] = (j0 + d <= row) ? rqm[d] * SCALE : 0.f;
    __syncthreads();   // khi^T reads done; arena reused for tkk/tT

    #pragma unroll
    for (int d = 0; d < 8; ++d) arena[row * 68 + j0 + d] = rk[d];
    __syncthreads();

    // T solve: (I + beta_i*strict_lower(kk)) T = diag(beta); lane j owns column j
    if (tid < 64) {
        const int j = tid;
        for (int i = 0; i < LCH; ++i) {
            float s = 0.f;
            for (int m = 0; m < i; ++m)
                s += arena[i * 68 + m] * arena[4352 + m * 68 + j];
            arena[4352 + i * 68 + j] = sbeta[i] * (((j == i) ? 1.f : 0.f) - s);
        }
    }
    __syncthreads();

    // T -> ws
    #pragma unroll
    for (int d = 0; d < 8; ++d)
        wT[chunk * 4096 + row * 64 + j0 + d] = arena[4352 + row * 68 + j0 + d];

    // fused G = qk_masked @ T  (qk row values broadcast from regs via shfl)
    {
        float g[8];
        #pragma unroll
        for (int d = 0; d < 8; ++d) g[d] = 0.f;
        for (int mb = 0; mb < 8; ++mb) {
            #pragma unroll
            for (int d = 0; d < 8; ++d) {
                const float a = __shfl(rqm[d], lb8 + mb);
                const int m = mb * 8 + d;
                const float4 t0 = *(const float4*)&arena[4352 + m * 68 + j0];
                const float4 t1 = *(const float4*)&arena[4352 + m * 68 + j0 + 4];
                g[0] += a * t0.x; g[1] += a * t0.y; g[2] += a * t0.z; g[3] += a * t0.w;
                g[4] += a * t1.x; g[5] += a * t1.y; g[6] += a * t1.z; g[7] += a * t1.w;
            }
        }
        #pragma unroll
        for (int d = 0; d < 8; ++d)
            wG[chunk * 4096 + row * 64 + j0 + d] = g[d];
    }
}

// ---------- Phase B: sequential scan; 32 chains x 16 column-groups of 8 ----------
// pass1: X = vg - khi@S ; O = Qn@S    pass2: corr = T@X ; O += G@X ; write O
// pass3: S = diag(egt)S + khi^T@corr
// 512 blocks x 512 threads (2 blocks/CU). Conflict-free padded LDS (stride 68/132),
// b128 LDS reads, next-chunk operands prefetched into registers (T14).
// LDS: sKhi 17408 + sQn 17408 + sT 17408 + sG 17408 + sSt 4224 + sXt 2176 + sCt 2176
//    = 78,208 B  -> 2 blocks/CU.
extern "C" __global__ __launch_bounds__(512)
void kda_phaseB(const u16* wkhi, const u16* wqn, const float* wT, const float* wG,
                const float* wegt, const float* wegcm, const float* gv, float* gout)
{
    __shared__ u32 sKhi[LCH][68];    // word w holds bf16 cols 2w, 2w+1
    __shared__ u32 sQn [LCH][68];
    __shared__ float sT[LCH][68];
    __shared__ float sG[LCH][68];
    __shared__ float sSt[8][132];    // S transposed: [col][k]
    __shared__ float sXt[8][68];     // X transposed: [col][row]
    __shared__ float sCt[8][68];     // corr transposed

    const int bh = blockIdx.x >> 4;
    const int c0 = (blockIdx.x & 15) * 8;
    const int tid = threadIdx.x;
    const int row = tid >> 3, p = tid & 7;   // pass1/2: 1 col (c0+p) per thread
    const int kx = tid >> 2, qq = tid & 3;   // pass3: row kx, cols 2qq,2qq+1

    for (int e = tid; e < 8 * 132; e += 512) ((float*)sSt)[e] = 0.f;

    float* outO = gout + (size_t)bh * (SEQ * CDIM);
    float* outS = gout + (size_t)NBH * SEQ * CDIM + (size_t)bh * (CDIM * CDIM);

    // prefetch registers (chunk 0)
    uint4 kA, kB, qA, qB;
    float4 tA, tB, gA, gB;
    float vN, emN, etN;
    {
        const int ch = bh * NCHK;
        const uint4* kp = (const uint4*)(wkhi + (size_t)ch * 8192 + row * CDIM + p * 16);
        kA = kp[0]; kB = kp[1];
        const uint4* qp = (const uint4*)(wqn + (size_t)ch * 8192 + row * CDIM + p * 16);
        qA = qp[0]; qB = qp[1];
        const float4* tp = (const float4*)(wT + (size_t)ch * 4096 + row * 64 + p * 8);
        tA = tp[0]; tB = tp[1];
        const float4* gp = (const float4*)(wG + (size_t)ch * 4096 + row * 64 + p * 8);
        gA = gp[0]; gB = gp[1];
        vN  = gv[(size_t)bh * SEQ * CDIM + (size_t)row * CDIM + c0 + p];
        emN = wegcm[ch * LCH + row];
        etN = wegt[ch * CDIM + kx];
    }

    for (int t = 0; t < NCHK; ++t) {
        // ---- stage (regs -> LDS) ----
        *(uint4*)&sKhi[row][p * 8]     = kA;
        *(uint4*)&sKhi[row][p * 8 + 4] = kB;
        *(uint4*)&sQn[row][p * 8]      = qA;
        *(uint4*)&sQn[row][p * 8 + 4]  = qB;
        *(float4*)&sT[row][p * 8]      = tA;
        *(float4*)&sT[row][p * 8 + 4]  = tB;
        *(float4*)&sG[row][p * 8]      = gA;
        *(float4*)&sG[row][p * 8 + 4]  = gB;
        const float vg = vN * emN;
        const float et = etN;
        __syncthreads();

        // ---- prefetch next chunk into registers (hidden under pass1-3) ----
        if (t + 1 < NCHK) {
            const int ch = bh * NCHK + t + 1;
            const uint4* kp = (const uint4*)(wkhi + (size_t)ch * 8192 + row * CDIM + p * 16);
            kA = kp[0]; kB = kp[1];
            const uint4* qp = (const uint4*)(wqn + (size_t)ch * 8192 + row * CDIM + p * 16);
            qA = qp[0]; qB = qp[1];
            const float4* tp = (const float4*)(wT + (size_t)ch * 4096 + row * 64 + p * 8);
            tA = tp[0]; tB = tp[1];
            const float4* gp = (const float4*)(wG + (size_t)ch * 4096 + row * 64 + p * 8);
            gA = gp[0]; gB = gp[1];
            vN  = gv[(size_t)bh * SEQ * CDIM + (size_t)((t + 1) * LCH + row) * CDIM + c0 + p];
            emN = wegcm[ch * LCH + row];
            etN = wegt[ch * CDIM + kx];
        }

        // ---- pass1: x = vg - khi_row · S_col ; o = Qn_row · S_col ----
        float x = vg, o = 0.f;
        #pragma unroll
        for (int j4 = 0; j4 < 16; ++j4) {
            const uint4 K = *(const uint4*)&sKhi[row][j4 * 4];
            const uint4 Q = *(const uint4*)&sQn[row][j4 * 4];
            const float4 Sa = *(const float4*)&sSt[p][j4 * 8];
            const float4 Sb = *(const float4*)&sSt[p][j4 * 8 + 4];
            x -= bf2f_bits(K.x & 0xffffu) * Sa.x + bf2f_bits(K.x >> 16) * Sa.y
               + bf2f_bits(K.y & 0xffffu) * Sa.z + bf2f_bits(K.y >> 16) * Sa.w
               + bf2f_bits(K.z & 0xffffu) * Sb.x + bf2f_bits(K.z >> 16) * Sb.y
               + bf2f_bits(K.w & 0xffffu) * Sb.z + bf2f_bits(K.w >> 16) * Sb.w;
            o += bf2f_bits(Q.x & 0xffffu) * Sa.x + bf2f_bits(Q.x >> 16) * Sa.y
               + bf2f_bits(Q.y & 0xffffu) * Sa.z + bf2f_bits(Q.y >> 16) * Sa.w
               + bf2f_bits(Q.z & 0xffffu) * Sb.x + bf2f_bits(Q.z >> 16) * Sb.y
               + bf2f_bits(Q.w & 0xffffu) * Sb.z + bf2f_bits(Q.w >> 16) * Sb.w;
        }
        sXt[p][row] = x;
        __syncthreads();

        // ---- pass2: corr = T@X ; O += G@X ; write O ----
        float cr = 0.f;
        #pragma unroll
        for (int m4 = 0; m4 < 16; ++m4) {
            const float4 T4 = *(const float4*)&sT[row][m4 * 4];
            const float4 G4 = *(const float4*)&sG[row][m4 * 4];
            const float4 X4 = *(const float4*)&sXt[p][m4 * 4];
            cr += T4.x * X4.x + T4.y * X4.y + T4.z * X4.z + T4.w * X4.w;
            o  += G4.x * X4.x + G4.y * X4.y + G4.z * X4.z + G4.w * X4.w;
        }
        sCt[p][row] = cr;
        outO[(size_t)(t * LCH + row) * CDIM + c0 + p] = o;
        __syncthreads();

        // ---- pass3: S = et*S + khi^T@corr (2 cols per thread) ----
        {
            float a0 = et * sSt[2 * qq][kx];
            float a1 = et * sSt[2 * qq + 1][kx];
            const int kw = kx >> 1, ksh = (kx & 1) * 16;
            #pragma unroll
            for (int i4 = 0; i4 < 16; ++i4) {
                const float4 C0 = *(const float4*)&sCt[2 * qq][i4 * 4];
                const float4 C1 = *(const float4*)&sCt[2 * qq + 1][i4 * 4];
                const float k0 = bf2f_bits((sKhi[i4 * 4 + 0][kw] >> ksh) & 0xffffu);
                const float k1 = bf2f_bits((sKhi[i4 * 4 + 1][kw] >> ksh) & 0xffffu);
                const float k2 = bf2f_bits((sKhi[i4 * 4 + 2][kw] >> ksh) & 0xffffu);
                const float k3 = bf2f_bits((sKhi[i4 * 4 + 3][kw] >> ksh) & 0xffffu);
                a0 += k0 * C0.x + k1 * C0.y + k2 * C0.z + k3 * C0.w;
                a1 += k0 * C1.x + k1 * C1.y + k2 * C1.z + k3 * C1.w;
            }
            sSt[2 * qq][kx]     = a0;
            sSt[2 * qq + 1][kx] = a1;
        }
        __syncthreads();
    }

    // final state
    outS[(size_t)kx * CDIM + c0 + 2 * qq]     = sSt[2 * qq][kx];
    outS[(size_t)kx * CDIM + c0 + 2 * qq + 1] = sSt[2 * qq + 1][kx];
}

extern "C" __attribute__((visibility("default")))
void kernel_launch(void* const* d_in, const int* in_sizes, int n_in,
                   void* d_out, int out_size, void* d_ws, size_t ws_size,
                   hipStream_t stream)
{
    (void)in_sizes; (void)n_in; (void)out_size;

    // stream validity guard (as in the passing round)
    hipStream_t s = stream;
    hipStreamCaptureStatus cs = hipStreamCaptureStatusNone;
    (void)hipStreamIsCapturing(stream, &cs);
    if (cs == hipStreamCaptureStatusNone) {
        hipError_t qe = hipStreamQuery(stream);
        if (qe != hipSuccess && qe != hipErrorNotReady) s = (hipStream_t)0;
    }

    const size_t NEED = (size_t)NCHUNKS * 8192 * 2 * 2     // khi + Qn (bf16)
                      + (size_t)NCHUNKS * 4096 * 4 * 2     // T + G (f32)
                      + (size_t)NCHUNKS * (CDIM + LCH) * 4;
    if (d_ws == 0 || ws_size < NEED) return;   // out stays zero -> visible failure

    const float* q    = (const float*)d_in[0];
    const float* k    = (const float*)d_in[1];
    const float* v    = (const float*)d_in[2];
    const float* g    = (const float*)d_in[3];
    const float* beta = (const float*)d_in[4];
    float* out = (float*)d_out;

    u16* wkhi    = (u16*)d_ws;
    u16* wqn     = wkhi + (size_t)NCHUNKS * 8192;
    float* wT    = (float*)(wqn + (size_t)NCHUNKS * 8192);
    float* wG    = wT + (size_t)NCHUNKS * 4096;
    float* wegt  = wG + (size_t)NCHUNKS * 4096;
    float* wegcm = wegt + (size_t)NCHUNKS * CDIM;

    kda_phaseA1<<<NCHUNKS, 512, 0, s>>>(q, k, g, beta, wkhi, wqn, wT, wG, wegt, wegcm);
    kda_phaseB<<<NBH * 16, 512, 0, s>>>(wkhi, wqn, wT, wG, wegt, wegcm, v, out);
}

// Round 9
// 348.006 us; speedup vs baseline: 1.4764x; 1.1559x over previous
//
#include <hip/hip_runtime.h>
#include <math.h>

// Problem constants (B=2, H=16, S=2048, K=V=128, CHUNK=64)
#define CDIM 128
#define LCH  64
#define NCHK 32
#define NBH  32
#define SEQ  2048
#define NCHUNKS 1024
#define SCALE 0.08838834764831845f

typedef unsigned short u16;
typedef unsigned int   u32;
typedef __attribute__((ext_vector_type(8))) short bf16x8;
typedef __attribute__((ext_vector_type(4))) float f32x4;

__device__ __forceinline__ u32 rne_bits(float x) {
    u32 u; __builtin_memcpy(&u, &x, 4);
    return u + 0x7fffu + ((u >> 16) & 1u);
}
__device__ __forceinline__ u32 pk_rne(float a, float b) {
    return (rne_bits(a) >> 16) | (rne_bits(b) & 0xffff0000u);
}
// split 8 f32 into hi (truncated bf16) + lo (residual, RNE bf16) fragment words
__device__ __forceinline__ void split8(const float* s, uint4& hi, uint4& lo) {
    u32 hw[4], lw[4];
    #pragma unroll
    for (int m = 0; m < 4; ++m) {
        u32 u0, u1;
        __builtin_memcpy(&u0, &s[2*m], 4);
        __builtin_memcpy(&u1, &s[2*m+1], 4);
        const u32 h0 = u0 & 0xffff0000u, h1 = u1 & 0xffff0000u;
        hw[m] = (h0 >> 16) | h1;
        float f0, f1;
        __builtin_memcpy(&f0, &h0, 4);
        __builtin_memcpy(&f1, &h1, 4);
        lw[m] = pk_rne(s[2*m] - f0, s[2*m+1] - f1);
    }
    hi.x = hw[0]; hi.y = hw[1]; hi.z = hw[2]; hi.w = hw[3];
    lo.x = lw[0]; lo.y = lw[1]; lo.z = lw[2]; lo.w = lw[3];
}
__device__ __forceinline__ f32x4 mfma_bf(uint4 a, uint4 b, f32x4 c) {
    union { uint4 u; bf16x8 v; } A, B;
    A.u = a; B.u = b;
    return __builtin_amdgcn_mfma_f32_16x16x32_bf16(A.v, B.v, c, 0, 0, 0);
}

// ---------- kept for symbol compatibility (not launched) ----------
extern "C" __global__ __launch_bounds__(256)
void KDABlock_4475355922517_kernel(float* out, int n, float val)
{
    int stride = gridDim.x * blockDim.x;
    for (int i = blockIdx.x * blockDim.x + threadIdx.x; i < n; i += stride)
        out[i] = val;
}

// ---------- Phase A: per-chunk quantities, emitted in MFMA A-fragment order ----------
// A-frag layout (16x16x32): word index ((mt*KS + ks)*64 + lane), lane holds 8 bf16:
//   element = M[16*mt + (lane&15)][32*ks + 8*(lane>>4) + j]
// Outputs: wKA  = -khi (64x128, KS=4), wQA = Qn (64x128), wKTA = khi^T (128x64, KS=2),
//          wTAh/l = T split (64x64), wGAh/l = G split (64x64), wegt(128), wegcm(64).
extern "C" __global__ __launch_bounds__(512)
void kda_phaseA(const float* gq, const float* gk, const float* gg, const float* gbeta,
                u16* wKA, u16* wQA, u16* wKTA,
                u16* wTAh, u16* wTAl, u16* wGAh, u16* wGAl,
                float* wegt, float* wegcm, int useLo)
{
    __shared__ float arena[8704];
    __shared__ float sbeta[64];

    const int chunk = blockIdx.x;
    const int bh = chunk >> 5, tt = chunk & 31;
    const int tid = threadIdx.x;
    const int base = bh * (SEQ * CDIM) + tt * (LCH * CDIM);
    const int row = tid >> 3, part = tid & 7;
    const int mtA = row >> 4, r15 = row & 15;
    const int j0 = part * 8;
    const int lb8 = (row & 7) << 3;

    // gcum: segmented cumsum over 64 rows per column (arena stride 130)
    {
        const int col = tid & 127, seg = tid >> 7;
        float acc = 0.f;
        for (int r = 0; r < 16; ++r) {
            const int i = seg * 16 + r;
            acc += gg[base + i * CDIM + col];
            arena[i * 130 + col] = acc;
        }
        __syncthreads();
        float off = 0.f;
        for (int s = 0; s < seg; ++s) off += arena[(s * 16 + 15) * 130 + col];
        __syncthreads();
        if (seg) for (int r = 0; r < 16; ++r) arena[(seg * 16 + r) * 130 + col] += off;
        if (tid < 64) sbeta[tid] = gbeta[bh * SEQ + tt * LCH + tid];
    }
    __syncthreads();

    float gc[16];
    #pragma unroll
    for (int c = 0; c < 16; ++c) gc[c] = arena[row * 130 + part * 16 + c];
    if (tid < 128) wegt[chunk * CDIM + tid] = __expf(arena[63 * 130 + tid]);
    float egr;
    {
        float s = 0.f;
        #pragma unroll
        for (int c = 0; c < 16; ++c) s += gc[c];
        s += __shfl_xor(s, 1); s += __shfl_xor(s, 2); s += __shfl_xor(s, 4);
        egr = __expf(s * (1.f / 128.f));
        if (part == 0) wegcm[chunk * LCH + row] = egr;
    }

    // k: normalize -> khi/klo; wKA frags (negated khi, single bf16)
    float khi[16], klo[16];
    {
        float ss = 0.f;
        const float* kp = gk + base + row * CDIM + part * 16;
        #pragma unroll
        for (int c = 0; c < 16; ++c) { khi[c] = kp[c]; ss += khi[c] * khi[c]; }
        ss += __shfl_xor(ss, 1); ss += __shfl_xor(ss, 2); ss += __shfl_xor(ss, 4);
        const float inv = 1.f / (sqrtf(ss) + 1e-6f);
        #pragma unroll
        for (int c = 0; c < 16; ++c) {
            const float kn = khi[c] * inv;
            khi[c] = kn * __expf(gc[c]);
            klo[c] = kn * __expf(-gc[c]);
        }
        const int ks = part >> 1;
        const int l0 = (2 * (part & 1)) * 16 + r15;
        uint4 w0, w1;
        w0.x = pk_rne(-khi[0], -khi[1]);   w0.y = pk_rne(-khi[2], -khi[3]);
        w0.z = pk_rne(-khi[4], -khi[5]);   w0.w = pk_rne(-khi[6], -khi[7]);
        w1.x = pk_rne(-khi[8], -khi[9]);   w1.y = pk_rne(-khi[10], -khi[11]);
        w1.z = pk_rne(-khi[12], -khi[13]); w1.w = pk_rne(-khi[14], -khi[15]);
        u16* d0 = wKA + (size_t)chunk * 8192 + (size_t)((mtA * 4 + ks) * 64 + l0) * 8;
        *(uint4*)d0 = w0;
        *(uint4*)(d0 + 128) = w1;
    }

    // q: normalize -> Qn frags (single bf16) ; qlo regs
    float qlo[16];
    {
        float qv[16], ss = 0.f;
        const float* qp = gq + base + row * CDIM + part * 16;
        #pragma unroll
        for (int c = 0; c < 16; ++c) { qv[c] = qp[c]; ss += qv[c] * qv[c]; }
        ss += __shfl_xor(ss, 1); ss += __shfl_xor(ss, 2); ss += __shfl_xor(ss, 4);
        const float inv = 1.f / (sqrtf(ss) + 1e-6f);
        const float qs = SCALE * egr * inv;
        const int ks = part >> 1;
        const int l0 = (2 * (part & 1)) * 16 + r15;
        uint4 w0, w1;
        w0.x = pk_rne(qv[0]*qs, qv[1]*qs);   w0.y = pk_rne(qv[2]*qs, qv[3]*qs);
        w0.z = pk_rne(qv[4]*qs, qv[5]*qs);   w0.w = pk_rne(qv[6]*qs, qv[7]*qs);
        w1.x = pk_rne(qv[8]*qs, qv[9]*qs);   w1.y = pk_rne(qv[10]*qs, qv[11]*qs);
        w1.z = pk_rne(qv[12]*qs, qv[13]*qs); w1.w = pk_rne(qv[14]*qs, qv[15]*qs);
        u16* d0 = wQA + (size_t)chunk * 8192 + (size_t)((mtA * 4 + ks) * 64 + l0) * 8;
        *(uint4*)d0 = w0;
        *(uint4*)(d0 + 128) = w1;
        #pragma unroll
        for (int c = 0; c < 16; ++c) qlo[c] = qv[c] * inv * __expf(-gc[c]);
    }
    __syncthreads();   // gcum readers done; arena reused

    // stage khi^T (f32, stride 68)
    #pragma unroll
    for (int c = 0; c < 16; ++c) arena[(part * 16 + c) * 68 + row] = khi[c];
    __syncthreads();

    // kk = klo@khi^T, qk = qlo@khi^T (row values via shfl broadcast)
    float rk[8], rqm[8];
    #pragma unroll
    for (int d = 0; d < 8; ++d) { rk[d] = 0.f; rqm[d] = 0.f; }
    for (int kb = 0; kb < 8; ++kb) {
        #pragma unroll
        for (int kc = 0; kc < 16; ++kc) {
            const int k2 = kb * 16 + kc;
            const float a = __shfl(klo[kc], lb8 + kb);
            const float b = __shfl(qlo[kc], lb8 + kb);
            const float* hp = &arena[k2 * 68 + j0];
            #pragma unroll
            for (int d = 0; d < 8; ++d) { rk[d] += a * hp[d]; rqm[d] += b * hp[d]; }
        }
    }
    #pragma unroll
    for (int d = 0; d < 8; ++d) rqm[d] = (j0 + d <= row) ? rqm[d] * SCALE : 0.f;
    __syncthreads();   // khi^T reads done

    #pragma unroll
    for (int d = 0; d < 8; ++d) arena[row * 68 + j0 + d] = rk[d];
    __syncthreads();

    // T solve: (I + beta_i*strict_lower(kk)) T = diag(beta); lane j owns column j
    if (tid < 64) {
        const int j = tid;
        for (int i = 0; i < LCH; ++i) {
            float s0 = 0.f, s1 = 0.f, s2 = 0.f, s3 = 0.f;
            int m = 0;
            for (; m + 4 <= i; m += 4) {
                s0 += arena[i*68 + m+0] * arena[4352 + (m+0)*68 + j];
                s1 += arena[i*68 + m+1] * arena[4352 + (m+1)*68 + j];
                s2 += arena[i*68 + m+2] * arena[4352 + (m+2)*68 + j];
                s3 += arena[i*68 + m+3] * arena[4352 + (m+3)*68 + j];
            }
            for (; m < i; ++m) s0 += arena[i*68 + m] * arena[4352 + m*68 + j];
            arena[4352 + i*68 + j] = sbeta[i] * (((j == i) ? 1.f : 0.f) - ((s0+s1)+(s2+s3)));
        }
    }
    __syncthreads();

    // T frags (split hi/lo): thread's natural slice T[row][8p..8p+7]; col 8p+j == 32ks+8h+j
    {
        const int ks = part >> 2;
        const int lT = (part & 3) * 16 + r15;
        const size_t off = (size_t)chunk * 4096 + (size_t)((mtA * 2 + ks) * 64 + lT) * 8;
        float tv[8];
        #pragma unroll
        for (int d = 0; d < 8; ++d) tv[d] = arena[4352 + row * 68 + j0 + d];
        uint4 hi, lo; split8(tv, hi, lo);
        *(uint4*)(wTAh + off) = hi;
        if (useLo) *(uint4*)(wTAl + off) = lo;
    }

    // G = qk_masked @ T -> frags (split hi/lo)
    {
        float g[8];
        #pragma unroll
        for (int d = 0; d < 8; ++d) g[d] = 0.f;
        for (int mb = 0; mb < 8; ++mb) {
            #pragma unroll
            for (int d = 0; d < 8; ++d) {
                const float a = __shfl(rqm[d], lb8 + mb);
                const int m = mb * 8 + d;
                const float* tp = &arena[4352 + m * 68 + j0];
                #pragma unroll
                for (int e = 0; e < 8; ++e) g[e] += a * tp[e];
            }
        }
        const int ks = part >> 2;
        const int lT = (part & 3) * 16 + r15;
        const size_t off = (size_t)chunk * 4096 + (size_t)((mtA * 2 + ks) * 64 + lT) * 8;
        uint4 hi, lo; split8(g, hi, lo);
        *(uint4*)(wGAh + off) = hi;
        if (useLo) *(uint4*)(wGAl + off) = lo;
    }
    __syncthreads();   // tT readers done; arena reused

    // restage khi^T and emit wKTA frags (khi^T is 128x64: mt 0..7, ks 0..1)
    #pragma unroll
    for (int c = 0; c < 16; ++c) arena[(part * 16 + c) * 68 + row] = khi[c];
    __syncthreads();
    #pragma unroll
    for (int gi = 0; gi < 2; ++gi) {
        const int gw = tid * 2 + gi;            // frag word 0..1023
        const int lw = gw & 63, ksw = (gw >> 6) & 1, mtw = gw >> 7;
        const int rr = 16 * mtw + (lw & 15);
        const int cb = 32 * ksw + 8 * (lw >> 4);
        float v[8];
        #pragma unroll
        for (int j = 0; j < 8; ++j) v[j] = arena[rr * 68 + cb + j];
        uint4 wv;
        wv.x = pk_rne(v[0], v[1]); wv.y = pk_rne(v[2], v[3]);
        wv.z = pk_rne(v[4], v[5]); wv.w = pk_rne(v[6], v[7]);
        *(uint4*)(wKTA + (size_t)chunk * 8192 + (size_t)gw * 8) = wv;
    }
}

// ---------- Phase B: MFMA scan; 256 blocks (32 bh x 8 colgroups of 16), 4 waves ----------
// pass1: X = vg - khi@S, O = Qn@S (S split hi/lo)   pass2: corr = T@X, O += G@X (T/G/X split)
// pass3: S = diag(egt)S + khi^T@corr (corr split)
extern "C" __global__ __launch_bounds__(256)
void kda_phaseB(const u16* wKA, const u16* wQA, const u16* wKTA,
                const u16* wTAh, const u16* wTAl, const u16* wGAh, const u16* wGAl,
                const float* wegt, const float* wegcm,
                const float* gv, float* gout, int useLo)
{
    __shared__ float sS[128 * 17];
    __shared__ float sX[64 * 17];
    __shared__ float sC[64 * 17];
    __shared__ float sEt[128];
    __shared__ float sEm[64];

    const int bh = blockIdx.x >> 3;
    const int c0 = (blockIdx.x & 7) * 16;
    const int tid = threadIdx.x;
    const int w = tid >> 6;       // wave 0..3 = M-tile
    const int l = tid & 63;
    const int ln = l & 15;
    const int lh = l >> 4;

    for (int e = tid; e < 128 * 17; e += 256) sS[e] = 0.f;

    float* outO = gout + (size_t)bh * (SEQ * CDIM);
    float* outS = gout + (size_t)NBH * SEQ * CDIM + (size_t)bh * (CDIM * CDIM);

    for (int t = 0; t < NCHK; ++t) {
        const size_t ch = (size_t)(bh * NCHK + t);

        // issue all A-fragment global loads early (coalesced dwordx4)
        uint4 kf[4], qf[4];
        const u16* pK = wKA + ch * 8192 + (size_t)w * 2048 + (size_t)l * 8;
        const u16* pQ = wQA + ch * 8192 + (size_t)w * 2048 + (size_t)l * 8;
        #pragma unroll
        for (int ks = 0; ks < 4; ++ks) {
            kf[ks] = *(const uint4*)(pK + ks * 512);
            qf[ks] = *(const uint4*)(pQ + ks * 512);
        }
        uint4 tfh[2], gfh[2], tfl[2], gfl[2];
        const size_t tb = ch * 4096 + (size_t)w * 1024 + (size_t)l * 8;
        #pragma unroll
        for (int ks = 0; ks < 2; ++ks) {
            tfh[ks] = *(const uint4*)(wTAh + tb + ks * 512);
            gfh[ks] = *(const uint4*)(wGAh + tb + ks * 512);
        }
        if (useLo) {
            #pragma unroll
            for (int ks = 0; ks < 2; ++ks) {
                tfl[ks] = *(const uint4*)(wTAl + tb + ks * 512);
                gfl[ks] = *(const uint4*)(wGAl + tb + ks * 512);
            }
        }
        uint4 ktf[2][2];
        #pragma unroll
        for (int m2 = 0; m2 < 2; ++m2)
            #pragma unroll
            for (int ks = 0; ks < 2; ++ks)
                ktf[m2][ks] = *(const uint4*)(wKTA + ch * 8192
                                + (size_t)((2*w + m2) * 2 + ks) * 512 + (size_t)l * 8);
        float vg[4];
        #pragma unroll
        for (int r = 0; r < 4; ++r) {
            const int row = 16 * w + 4 * lh + r;
            vg[r] = gv[(size_t)bh * SEQ * CDIM + (size_t)(t * LCH + row) * CDIM + c0 + ln];
        }
        if (tid < 128) sEt[tid] = wegt[ch * CDIM + tid];
        else if (tid < 192) sEm[tid - 128] = wegcm[ch * LCH + (tid - 128)];
        __syncthreads();   // barrier A: S(prev), sEt/sEm ready

        f32x4 accX, accO;
        #pragma unroll
        for (int r = 0; r < 4; ++r) {
            accX[r] = vg[r] * sEm[16 * w + 4 * lh + r];
            accO[r] = 0.f;
        }

        // pass1: X = vg + (-khi)@S ; O = Qn@S   (S split)
        #pragma unroll
        for (int ks = 0; ks < 4; ++ks) {
            float sv[8];
            const int kb = 32 * ks + 8 * lh;
            #pragma unroll
            for (int j = 0; j < 8; ++j) sv[j] = sS[(kb + j) * 17 + ln];
            uint4 hi, lo; split8(sv, hi, lo);
            accX = mfma_bf(kf[ks], hi, accX);
            accX = mfma_bf(kf[ks], lo, accX);
            accO = mfma_bf(qf[ks], hi, accO);
            accO = mfma_bf(qf[ks], lo, accO);
        }
        #pragma unroll
        for (int r = 0; r < 4; ++r) sX[(16 * w + 4 * lh + r) * 17 + ln] = accX[r];
        __syncthreads();   // barrier B

        // pass2: corr = T@X ; O += G@X   (X split; T/G hi + optional lo)
        f32x4 accC = {0.f, 0.f, 0.f, 0.f};
        #pragma unroll
        for (int ks = 0; ks < 2; ++ks) {
            float xv[8];
            const int kb = 32 * ks + 8 * lh;
            #pragma unroll
            for (int j = 0; j < 8; ++j) xv[j] = sX[(kb + j) * 17 + ln];
            uint4 xh, xl; split8(xv, xh, xl);
            accC = mfma_bf(tfh[ks], xh, accC);
            accC = mfma_bf(tfh[ks], xl, accC);
            accO = mfma_bf(gfh[ks], xh, accO);
            accO = mfma_bf(gfh[ks], xl, accO);
            if (useLo) {
                accC = mfma_bf(tfl[ks], xh, accC);
                accO = mfma_bf(gfl[ks], xh, accO);
            }
        }
        #pragma unroll
        for (int r = 0; r < 4; ++r) {
            const int row = 16 * w + 4 * lh + r;
            outO[(size_t)(t * LCH + row) * CDIM + c0 + ln] = accO[r];
            sC[row * 17 + ln] = accC[r];
        }
        __syncthreads();   // barrier C

        // pass3: S = diag(egt)S + khi^T@corr   (corr split)
        uint4 csh[2], csl[2];
        #pragma unroll
        for (int ks = 0; ks < 2; ++ks) {
            float cv[8];
            const int kb = 32 * ks + 8 * lh;
            #pragma unroll
            for (int j = 0; j < 8; ++j) cv[j] = sC[(kb + j) * 17 + ln];
            split8(cv, csh[ks], csl[ks]);
        }
        #pragma unroll
        for (int m2 = 0; m2 < 2; ++m2) {
            const int mt = 2 * w + m2;
            f32x4 accS;
            #pragma unroll
            for (int r = 0; r < 4; ++r) {
                const int row = 16 * mt + 4 * lh + r;
                accS[r] = sEt[row] * sS[row * 17 + ln];
            }
            #pragma unroll
            for (int ks = 0; ks < 2; ++ks) {
                accS = mfma_bf(ktf[m2][ks], csh[ks], accS);
                accS = mfma_bf(ktf[m2][ks], csl[ks], accS);
            }
            #pragma unroll
            for (int r = 0; r < 4; ++r) {
                const int row = 16 * mt + 4 * lh + r;
                sS[row * 17 + ln] = accS[r];
            }
        }
        __syncthreads();   // barrier D (protects sEt/sEm restage + S)
    }

    // final state
    {
        const int col = tid & 15, rb = (tid >> 4) * 8;
        #pragma unroll
        for (int r = 0; r < 8; ++r)
            outS[(size_t)(rb + r) * CDIM + c0 + col] = sS[(rb + r) * 17 + col];
    }
}

extern "C" __attribute__((visibility("default")))
void kernel_launch(void* const* d_in, const int* in_sizes, int n_in,
                   void* d_out, int out_size, void* d_ws, size_t ws_size,
                   hipStream_t stream)
{
    (void)in_sizes; (void)n_in; (void)out_size;

    // stream validity guard (as in the passing rounds)
    hipStream_t s = stream;
    hipStreamCaptureStatus cs = hipStreamCaptureStatusNone;
    (void)hipStreamIsCapturing(stream, &cs);
    if (cs == hipStreamCaptureStatusNone) {
        hipError_t qe = hipStreamQuery(stream);
        if (qe != hipSuccess && qe != hipErrorNotReady) s = (hipStream_t)0;
    }

    // Base layout (proven footprint, == round-7's 67,895,296 B):
    //   wKA,wQA,wKTA: 8192 u16/chunk; wTAh,wGAh: 4096 u16/chunk; egt/egcm f32.
    // Optional lo frags appended: +16.8 MB.
    const size_t NEED_base = (size_t)NCHUNKS * (8192*3 + 4096*2) * 2
                           + (size_t)NCHUNKS * (CDIM + LCH) * 4;
    const size_t NEED_full = NEED_base + (size_t)NCHUNKS * 4096 * 2 * 2;
    if (d_ws == 0 || ws_size < NEED_base) return;   // visible failure (zeros)
    const int useLo = (ws_size >= NEED_full) ? 1 : 0;

    const float* q    = (const float*)d_in[0];
    const float* k    = (const float*)d_in[1];
    const float* v    = (const float*)d_in[2];
    const float* g    = (const float*)d_in[3];
    const float* beta = (const float*)d_in[4];
    float* out = (float*)d_out;

    u16* wKA   = (u16*)d_ws;
    u16* wQA   = wKA  + (size_t)NCHUNKS * 8192;
    u16* wKTA  = wQA  + (size_t)NCHUNKS * 8192;
    u16* wTAh  = wKTA + (size_t)NCHUNKS * 8192;
    u16* wGAh  = wTAh + (size_t)NCHUNKS * 4096;
    float* wegt  = (float*)(wGAh + (size_t)NCHUNKS * 4096);
    float* wegcm = wegt + (size_t)NCHUNKS * CDIM;
    u16* wTAl  = (u16*)(wegcm + (size_t)NCHUNKS * LCH);
    u16* wGAl  = wTAl + (size_t)NCHUNKS * 4096;
    if (!useLo) { wTAl = wTAh; wGAl = wGAh; }   // valid but unused pointers

    kda_phaseA<<<NCHUNKS, 512, 0, s>>>(q, k, g, beta, wKA, wQA, wKTA,
                                       wTAh, wTAl, wGAh, wGAl, wegt, wegcm, useLo);
    kda_phaseB<<<NBH * 8, 256, 0, s>>>(wKA, wQA, wKTA, wTAh, wTAl, wGAh, wGAl,
                                       wegt, wegcm, v, out, useLo);
}

// Round 11
// 300.273 us; speedup vs baseline: 1.7111x; 1.1590x over previous
//
#include <hip/hip_runtime.h>
#include <math.h>

// Problem constants (B=2, H=16, S=2048, K=V=128, CHUNK=64)
#define CDIM 128
#define LCH  64
#define NCHK 32
#define NBH  32
#define SEQ  2048
#define NCHUNKS 1024
#define SCALE 0.08838834764831845f

typedef unsigned short u16;
typedef unsigned int   u32;
typedef __attribute__((ext_vector_type(8))) short bf16x8;
typedef __attribute__((ext_vector_type(4))) float f32x4;

__device__ __forceinline__ u16 f2bf(float f) {
    u32 u; __builtin_memcpy(&u, &f, 4);
    u32 r = u + 0x7fffu + ((u >> 16) & 1u);   // RNE
    return (u16)(r >> 16);
}
__device__ __forceinline__ u32 rne_bits(float x) {
    u32 u; __builtin_memcpy(&u, &x, 4);
    return u + 0x7fffu + ((u >> 16) & 1u);
}
__device__ __forceinline__ u32 pk_rne(float a, float b) {
    return (rne_bits(a) >> 16) | (rne_bits(b) & 0xffff0000u);
}
// split pair of f32 into hi (truncated bf16 pair) + lo (residual RNE bf16 pair)
__device__ __forceinline__ void split2(float a, float b, u32& hw, u32& lw) {
    u32 u0, u1;
    __builtin_memcpy(&u0, &a, 4);
    __builtin_memcpy(&u1, &b, 4);
    const u32 h0 = u0 & 0xffff0000u, h1 = u1 & 0xffff0000u;
    hw = (h0 >> 16) | h1;
    float f0, f1;
    __builtin_memcpy(&f0, &h0, 4);
    __builtin_memcpy(&f1, &h1, 4);
    lw = pk_rne(a - f0, b - f1);
}
__device__ __forceinline__ void split8(const float* s, uint4& hi, uint4& lo) {
    u32 hw[4], lw[4];
    #pragma unroll
    for (int m = 0; m < 4; ++m) split2(s[2*m], s[2*m+1], hw[m], lw[m]);
    hi.x = hw[0]; hi.y = hw[1]; hi.z = hw[2]; hi.w = hw[3];
    lo.x = lw[0]; lo.y = lw[1]; lo.z = lw[2]; lo.w = lw[3];
}
__device__ __forceinline__ f32x4 mfma_bf(uint4 a, uint4 b, f32x4 c) {
    union { uint4 u; bf16x8 v; } A, B;
    A.u = a; B.u = b;
    return __builtin_amdgcn_mfma_f32_16x16x32_bf16(A.v, B.v, c, 0, 0, 0);
}

// ---------- kept for symbol compatibility (not launched) ----------
extern "C" __global__ __launch_bounds__(256)
void KDABlock_4475355922517_kernel(float* out, int n, float val)
{
    int stride = gridDim.x * blockDim.x;
    for (int i = blockIdx.x * blockDim.x + threadIdx.x; i < n; i += stride)
        out[i] = val;
}

// ---------- Phase A1 (round-8 verbatim, replay-proven ~85us) ----------
// Writes: khi (64x128 bf16 row-major), Qn (64x128 bf16 row-major),
//         T (64x64 f32 row-major), G (64x64 f32 row-major, fused),
//         egt (128 f32), egcm (64 f32).
extern "C" __global__ __launch_bounds__(512)
void kda_phaseA1(const float* gq, const float* gk, const float* gg, const float* gbeta,
                 u16* wkhi, u16* wqn, float* wT, float* wG, float* wegt, float* wegcm)
{
    __shared__ float arena[8704];
    __shared__ float sbeta[64];

    const int chunk = blockIdx.x;
    const int bh = chunk >> 5, tt = chunk & 31;
    const int tid = threadIdx.x;
    const int base = bh * (SEQ * CDIM) + tt * (LCH * CDIM);
    const int row = tid >> 3, part = tid & 7;

    // gcum: segmented cumsum over 64 rows per column (arena stride 130)
    {
        const int col = tid & 127, seg = tid >> 7;
        float acc = 0.f;
        for (int r = 0; r < 16; ++r) {
            const int i = seg * 16 + r;
            acc += gg[base + i * CDIM + col];
            arena[i * 130 + col] = acc;
        }
        __syncthreads();
        float off = 0.f;
        for (int s = 0; s < seg; ++s) off += arena[(s * 16 + 15) * 130 + col];
        __syncthreads();
        if (seg) for (int r = 0; r < 16; ++r) arena[(seg * 16 + r) * 130 + col] += off;
        if (tid < 64) sbeta[tid] = gbeta[bh * SEQ + tt * LCH + tid];
    }
    __syncthreads();

    // gcum -> registers; egt; egcm
    float gc[16];
    #pragma unroll
    for (int c = 0; c < 16; ++c) gc[c] = arena[row * 130 + part * 16 + c];
    if (tid < 128) wegt[chunk * CDIM + tid] = __expf(arena[63 * 130 + tid]);
    float egr;
    {
        float s = 0.f;
        #pragma unroll
        for (int c = 0; c < 16; ++c) s += gc[c];
        s += __shfl_xor(s, 1); s += __shfl_xor(s, 2); s += __shfl_xor(s, 4);
        egr = __expf(s * (1.f / 128.f));
        if (part == 0) wegcm[chunk * LCH + row] = egr;
    }

    // k: normalize -> khi/klo regs; khi -> ws (bf16)
    float khi[16], klo[16];
    {
        float ss = 0.f;
        const float* kp = gk + base + row * CDIM + part * 16;
        #pragma unroll
        for (int c = 0; c < 16; ++c) { khi[c] = kp[c]; ss += khi[c] * khi[c]; }
        ss += __shfl_xor(ss, 1); ss += __shfl_xor(ss, 2); ss += __shfl_xor(ss, 4);
        const float inv = 1.f / (sqrtf(ss) + 1e-6f);
        #pragma unroll
        for (int c = 0; c < 16; ++c) {
            const float kn = khi[c] * inv;
            khi[c] = kn * __expf(gc[c]);
            klo[c] = kn * __expf(-gc[c]);
            wkhi[chunk * 8192 + row * CDIM + part * 16 + c] = f2bf(khi[c]);
        }
    }

    // q: normalize -> qlo regs; Qn -> ws (bf16)
    float qlo[16];
    {
        float ss = 0.f;
        const float* qp = gq + base + row * CDIM + part * 16;
        #pragma unroll
        for (int c = 0; c < 16; ++c) { qlo[c] = qp[c]; ss += qlo[c] * qlo[c]; }
        ss += __shfl_xor(ss, 1); ss += __shfl_xor(ss, 2); ss += __shfl_xor(ss, 4);
        const float inv = 1.f / (sqrtf(ss) + 1e-6f);
        const float qs = SCALE * egr * inv;
        #pragma unroll
        for (int c = 0; c < 16; ++c) {
            wqn[chunk * 8192 + row * CDIM + part * 16 + c] = f2bf(qlo[c] * qs);
            qlo[c] = qlo[c] * inv * __expf(-gc[c]);
        }
    }
    __syncthreads();   // gcum readers done; arena reused

    // stage khi^T: arena[k*68 + r] = khi[r][k]
    #pragma unroll
    for (int c = 0; c < 16; ++c) arena[(part * 16 + c) * 68 + row] = khi[c];
    __syncthreads();

    // kk = klo@khi^T, qk = qlo@khi^T (row values via shfl broadcast)
    float rk[8], rqm[8];
    #pragma unroll
    for (int d = 0; d < 8; ++d) { rk[d] = 0.f; rqm[d] = 0.f; }
    const int j0 = part * 8;
    const int lb8 = (row & 7) << 3;
    for (int kb = 0; kb < 8; ++kb) {
        #pragma unroll
        for (int kc = 0; kc < 16; ++kc) {
            const int k2 = kb * 16 + kc;
            const float a = __shfl(klo[kc], lb8 + kb);
            const float b = __shfl(qlo[kc], lb8 + kb);
            const float* hp = &arena[k2 * 68 + j0];
            #pragma unroll
            for (int d = 0; d < 8; ++d) { rk[d] += a * hp[d]; rqm[d] += b * hp[d]; }
        }
    }
    #pragma unroll
    for (int d = 0; d < 8; ++d) rqm[d] = (j0 + d <= row) ? rqm[d] * SCALE : 0.f;
    __syncthreads();   // khi^T reads done; arena reused for tkk/tT

    #pragma unroll
    for (int d = 0; d < 8; ++d) arena[row * 68 + j0 + d] = rk[d];
    __syncthreads();

    // T solve: (I + beta_i*strict_lower(kk)) T = diag(beta); lane j owns column j
    if (tid < 64) {
        const int j = tid;
        for (int i = 0; i < LCH; ++i) {
            float s0 = 0.f, s1 = 0.f, s2 = 0.f, s3 = 0.f;
            int m = 0;
            for (; m + 4 <= i; m += 4) {
                s0 += arena[i*68 + m+0] * arena[4352 + (m+0)*68 + j];
                s1 += arena[i*68 + m+1] * arena[4352 + (m+1)*68 + j];
                s2 += arena[i*68 + m+2] * arena[4352 + (m+2)*68 + j];
                s3 += arena[i*68 + m+3] * arena[4352 + (m+3)*68 + j];
            }
            for (; m < i; ++m) s0 += arena[i*68 + m] * arena[4352 + m*68 + j];
            arena[4352 + i*68 + j] = sbeta[i] * (((j == i) ? 1.f : 0.f) - ((s0+s1)+(s2+s3)));
        }
    }
    __syncthreads();

    // T -> ws (f32 row-major)
    #pragma unroll
    for (int d = 0; d < 8; ++d)
        wT[chunk * 4096 + row * 64 + j0 + d] = arena[4352 + row * 68 + j0 + d];

    // fused G = qk_masked @ T -> ws (f32 row-major)
    {
        float g[8];
        #pragma unroll
        for (int d = 0; d < 8; ++d) g[d] = 0.f;
        for (int mb = 0; mb < 8; ++mb) {
            #pragma unroll
            for (int d = 0; d < 8; ++d) {
                const float a = __shfl(rqm[d], lb8 + mb);
                const int m = mb * 8 + d;
                const float4 t0 = *(const float4*)&arena[4352 + m * 68 + j0];
                const float4 t1 = *(const float4*)&arena[4352 + m * 68 + j0 + 4];
                g[0] += a * t0.x; g[1] += a * t0.y; g[2] += a * t0.z; g[3] += a * t0.w;
                g[4] += a * t1.x; g[5] += a * t1.y; g[6] += a * t1.z; g[7] += a * t1.w;
            }
        }
        #pragma unroll
        for (int d = 0; d < 8; ++d)
            wG[chunk * 4096 + row * 64 + j0 + d] = g[d];
    }
}

// ---------- Phase A2: repack row-major -> MFMA fragment order (in place) ----------
// All loads -> one barrier -> all stores. No LDS, no cross-thread dataflow.
// slot1: khi -> wKA(-khi frags). slot2: Qn -> wQA frags.
// slot3 (as u16, stride 8192/chunk): T f32 -> [TAh(4096) | GAh(4096)].
// slot4 (as u16, stride 8192/chunk): G f32 -> wKTA (khi^T frags).
// Optional dense lo frags: wTAl/wGAl (stride 4096/chunk).
extern "C" __global__ __launch_bounds__(256)
void kda_phaseA2(u16* slot1, u16* slot2, float* wTf, float* wGf,
                 u16* wTAl, u16* wGAl, int useLo)
{
    const int chunk = blockIdx.x;
    const int tid = threadIdx.x;
    const size_t cb16 = (size_t)chunk * 8192;   // u16 offset for slot1/2/3u/4u
    const size_t cbf  = (size_t)chunk * 4096;   // f32 offset for slot3/4 reads

    u16* slot3u = (u16*)wTf;
    u16* slot4u = (u16*)wGf;

    // ---- load phase ----
    uint4 ka[4], qa[4];
    #pragma unroll
    for (int i = 0; i < 4; ++i) {
        const int fw = tid + 256 * i;           // KA/QA frag word 0..1023
        const int mt = fw >> 8, ks = (fw >> 6) & 3, l = fw & 63;
        const size_t src = cb16 + (size_t)(16 * mt + (l & 15)) * 128 + 32 * ks + 8 * (l >> 4);
        ka[i] = *(const uint4*)(slot1 + src);
        qa[i] = *(const uint4*)(slot2 + src);
    }
    u32 kt[4][4];                               // wKTA gathers (khi^T frags)
    #pragma unroll
    for (int i = 0; i < 4; ++i) {
        const int fw = tid + 256 * i;           // KTA frag word 0..1023
        const int mt = fw >> 7, ks = (fw >> 6) & 1, l = fw & 63;
        const int col = 16 * mt + (l & 15);
        const int rb = 32 * ks + 8 * (l >> 4);
        #pragma unroll
        for (int p = 0; p < 4; ++p) {
            const u16 a = slot1[cb16 + (size_t)(rb + 2 * p) * 128 + col];
            const u16 b = slot1[cb16 + (size_t)(rb + 2 * p + 1) * 128 + col];
            kt[i][p] = (u32)a | ((u32)b << 16);
        }
    }
    float tv[2][8], gv2[2][8];
    #pragma unroll
    for (int i = 0; i < 2; ++i) {
        const int fw = tid + 256 * i;           // T/G frag word 0..511
        const int mt = fw >> 7, ks = (fw >> 6) & 1, l = fw & 63;
        const size_t src = cbf + (size_t)(16 * mt + (l & 15)) * 64 + 32 * ks + 8 * (l >> 4);
        *(float4*)&tv[i][0]  = *(const float4*)(wTf + src);
        *(float4*)&tv[i][4]  = *(const float4*)(wTf + src + 4);
        *(float4*)&gv2[i][0] = *(const float4*)(wGf + src);
        *(float4*)&gv2[i][4] = *(const float4*)(wGf + src + 4);
    }
    __syncthreads();   // all loads complete before any in-place store

    // ---- store phase ----
    #pragma unroll
    for (int i = 0; i < 4; ++i) {
        const int fw = tid + 256 * i;
        uint4 kv = ka[i];
        kv.x ^= 0x80008000u; kv.y ^= 0x80008000u;   // exact negation of bf16 pairs
        kv.z ^= 0x80008000u; kv.w ^= 0x80008000u;
        *(uint4*)(slot1 + cb16 + (size_t)fw * 8) = kv;
        *(uint4*)(slot2 + cb16 + (size_t)fw * 8) = qa[i];
        uint4 kw;
        kw.x = kt[i][0]; kw.y = kt[i][1]; kw.z = kt[i][2]; kw.w = kt[i][3];
        *(uint4*)(slot4u + cb16 + (size_t)fw * 8) = kw;
    }
    #pragma unroll
    for (int i = 0; i < 2; ++i) {
        const int fw = tid + 256 * i;
        uint4 th, tl, gh, gl;
        split8(tv[i],  th, tl);
        split8(gv2[i], gh, gl);
        *(uint4*)(slot3u + cb16 + (size_t)fw * 8) = th;            // TAh
        *(uint4*)(slot3u + cb16 + 4096 + (size_t)fw * 8) = gh;     // GAh
        if (useLo) {
            *(uint4*)(wTAl + cbf + (size_t)fw * 8) = tl;
            *(uint4*)(wGAl + cbf + (size_t)fw * 8) = gl;
        }
    }
}

// ---------- Phase B: MFMA scan (round-9 verbatim; only TAh/GAh addressing changed) ----------
extern "C" __global__ __launch_bounds__(256)
void kda_phaseB(const u16* wKA, const u16* wQA, const u16* wKTA,
                const u16* wTGh, const u16* wTAl, const u16* wGAl,
                const float* wegt, const float* wegcm,
                const float* gv, float* gout, int useLo)
{
    __shared__ float sS[128 * 17];
    __shared__ float sX[64 * 17];
    __shared__ float sC[64 * 17];
    __shared__ float sEt[128];
    __shared__ float sEm[64];

    const int bh = blockIdx.x >> 3;
    const int c0 = (blockIdx.x & 7) * 16;
    const int tid = threadIdx.x;
    const int w = tid >> 6;       // wave 0..3 = M-tile
    const int l = tid & 63;
    const int ln = l & 15;
    const int lh = l >> 4;

    for (int e = tid; e < 128 * 17; e += 256) sS[e] = 0.f;

    float* outO = gout + (size_t)bh * (SEQ * CDIM);
    float* outS = gout + (size_t)NBH * SEQ * CDIM + (size_t)bh * (CDIM * CDIM);

    for (int t = 0; t < NCHK; ++t) {
        const size_t ch = (size_t)(bh * NCHK + t);

        uint4 kf[4], qf[4];
        const u16* pK = wKA + ch * 8192 + (size_t)w * 2048 + (size_t)l * 8;
        const u16* pQ = wQA + ch * 8192 + (size_t)w * 2048 + (size_t)l * 8;
        #pragma unroll
        for (int ks = 0; ks < 4; ++ks) {
            kf[ks] = *(const uint4*)(pK + ks * 512);
            qf[ks] = *(const uint4*)(pQ + ks * 512);
        }
        uint4 tfh[2], gfh[2], tfl[2], gfl[2];
        const size_t tb = ch * 8192 + (size_t)w * 1024 + (size_t)l * 8;   // TAh|GAh slot
        #pragma unroll
        for (int ks = 0; ks < 2; ++ks) {
            tfh[ks] = *(const uint4*)(wTGh + tb + ks * 512);
            gfh[ks] = *(const uint4*)(wTGh + tb + 4096 + ks * 512);
        }
        if (useLo) {
            const size_t tbl = ch * 4096 + (size_t)w * 1024 + (size_t)l * 8;
            #pragma unroll
            for (int ks = 0; ks < 2; ++ks) {
                tfl[ks] = *(const uint4*)(wTAl + tbl + ks * 512);
                gfl[ks] = *(const uint4*)(wGAl + tbl + ks * 512);
            }
        }
        uint4 ktf[2][2];
        #pragma unroll
        for (int m2 = 0; m2 < 2; ++m2)
            #pragma unroll
            for (int ks = 0; ks < 2; ++ks)
                ktf[m2][ks] = *(const uint4*)(wKTA + ch * 8192
                                + (size_t)((2*w + m2) * 2 + ks) * 512 + (size_t)l * 8);
        float vg[4];
        #pragma unroll
        for (int r = 0; r < 4; ++r) {
            const int row = 16 * w + 4 * lh + r;
            vg[r] = gv[(size_t)bh * SEQ * CDIM + (size_t)(t * LCH + row) * CDIM + c0 + ln];
        }
        if (tid < 128) sEt[tid] = wegt[ch * CDIM + tid];
        else if (tid < 192) sEm[tid - 128] = wegcm[ch * LCH + (tid - 128)];
        __syncthreads();   // barrier A

        f32x4 accX, accO;
        #pragma unroll
        for (int r = 0; r < 4; ++r) {
            accX[r] = vg[r] * sEm[16 * w + 4 * lh + r];
            accO[r] = 0.f;
        }

        // pass1: X = vg + (-khi)@S ; O = Qn@S   (S split)
        #pragma unroll
        for (int ks = 0; ks < 4; ++ks) {
            float sv[8];
            const int kb = 32 * ks + 8 * lh;
            #pragma unroll
            for (int j = 0; j < 8; ++j) sv[j] = sS[(kb + j) * 17 + ln];
            uint4 hi, lo; split8(sv, hi, lo);
            accX = mfma_bf(kf[ks], hi, accX);
            accX = mfma_bf(kf[ks], lo, accX);
            accO = mfma_bf(qf[ks], hi, accO);
            accO = mfma_bf(qf[ks], lo, accO);
        }
        #pragma unroll
        for (int r = 0; r < 4; ++r) sX[(16 * w + 4 * lh + r) * 17 + ln] = accX[r];
        __syncthreads();   // barrier B

        // pass2: corr = T@X ; O += G@X
        f32x4 accC = {0.f, 0.f, 0.f, 0.f};
        #pragma unroll
        for (int ks = 0; ks < 2; ++ks) {
            float xv[8];
            const int kb = 32 * ks + 8 * lh;
            #pragma unroll
            for (int j = 0; j < 8; ++j) xv[j] = sX[(kb + j) * 17 + ln];
            uint4 xh, xl; split8(xv, xh, xl);
            accC = mfma_bf(tfh[ks], xh, accC);
            accC = mfma_bf(tfh[ks], xl, accC);
            accO = mfma_bf(gfh[ks], xh, accO);
            accO = mfma_bf(gfh[ks], xl, accO);
            if (useLo) {
                accC = mfma_bf(tfl[ks], xh, accC);
                accO = mfma_bf(gfl[ks], xh, accO);
            }
        }
        #pragma unroll
        for (int r = 0; r < 4; ++r) {
            const int row = 16 * w + 4 * lh + r;
            outO[(size_t)(t * LCH + row) * CDIM + c0 + ln] = accO[r];
            sC[row * 17 + ln] = accC[r];
        }
        __syncthreads();   // barrier C

        // pass3: S = diag(egt)S + khi^T@corr
        uint4 csh[2], csl[2];
        #pragma unroll
        for (int ks = 0; ks < 2; ++ks) {
            float cv[8];
            const int kb = 32 * ks + 8 * lh;
            #pragma unroll
            for (int j = 0; j < 8; ++j) cv[j] = sC[(kb + j) * 17 + ln];
            split8(cv, csh[ks], csl[ks]);
        }
        #pragma unroll
        for (int m2 = 0; m2 < 2; ++m2) {
            const int mt = 2 * w + m2;
            f32x4 accS;
            #pragma unroll
            for (int r = 0; r < 4; ++r) {
                const int row = 16 * mt + 4 * lh + r;
                accS[r] = sEt[row] * sS[row * 17 + ln];
            }
            #pragma unroll
            for (int ks = 0; ks < 2; ++ks) {
                accS = mfma_bf(ktf[m2][ks], csh[ks], accS);
                accS = mfma_bf(ktf[m2][ks], csl[ks], accS);
            }
            #pragma unroll
            for (int r = 0; r < 4; ++r) {
                const int row = 16 * mt + 4 * lh + r;
                sS[row * 17 + ln] = accS[r];
            }
        }
        __syncthreads();   // barrier D
    }

    // final state
    {
        const int col = tid & 15, rb = (tid >> 4) * 8;
        #pragma unroll
        for (int r = 0; r < 8; ++r)
            outS[(size_t)(rb + r) * CDIM + c0 + col] = sS[(rb + r) * 17 + col];
    }
}

extern "C" __attribute__((visibility("default")))
void kernel_launch(void* const* d_in, const int* in_sizes, int n_in,
                   void* d_out, int out_size, void* d_ws, size_t ws_size,
                   hipStream_t stream)
{
    (void)in_sizes; (void)n_in; (void)out_size;

    // Base = 67,895,296 B (round-7-proven). Optional lo frags: +16,777,216.
    const size_t NEED1 = (size_t)NCHUNKS * (8192*2*2 + 4096*4*2)
                       + (size_t)NCHUNKS * (CDIM + LCH) * 4;
    const size_t NEED2 = NEED1 + (size_t)NCHUNKS * 4096 * 2 * 2;
    if (d_ws == 0 || ws_size < NEED1) return;   // visible failure (zeros)
    const int useLo = (ws_size >= NEED2) ? 1 : 0;

    const float* q    = (const float*)d_in[0];
    const float* k    = (const float*)d_in[1];
    const float* v    = (const float*)d_in[2];
    const float* g    = (const float*)d_in[3];
    const float* beta = (const float*)d_in[4];
    float* out = (float*)d_out;

    u16* slot1   = (u16*)d_ws;                              // khi -> wKA
    u16* slot2   = slot1 + (size_t)NCHUNKS * 8192;          // Qn  -> wQA
    float* wT    = (float*)(slot2 + (size_t)NCHUNKS * 8192);// T   -> TAh|GAh
    float* wG    = wT + (size_t)NCHUNKS * 4096;             // G   -> wKTA
    float* wegt  = wG + (size_t)NCHUNKS * 4096;
    float* wegcm = wegt + (size_t)NCHUNKS * CDIM;
    u16* wTAl    = (u16*)(wegcm + (size_t)NCHUNKS * LCH);
    u16* wGAl    = wTAl + (size_t)NCHUNKS * 4096;
    if (!useLo) { wTAl = slot1; wGAl = slot1; }   // valid but unused

    kda_phaseA1<<<NCHUNKS, 512, 0, stream>>>(q, k, g, beta, slot1, slot2,
                                             wT, wG, wegt, wegcm);
    kda_phaseA2<<<NCHUNKS, 256, 0, stream>>>(slot1, slot2, wT, wG,
                                             wTAl, wGAl, useLo);
    kda_phaseB<<<NBH * 8, 256, 0, stream>>>(slot1, slot2, (u16*)wG, (u16*)wT,
                                            wTAl, wGAl, wegt, wegcm, v, out, useLo);
}

// Round 12
// 264.504 us; speedup vs baseline: 1.9425x; 1.1352x over previous
//
#include <hip/hip_runtime.h>
#include <math.h>

// Problem constants (B=2, H=16, S=2048, K=V=128, CHUNK=64)
#define CDIM 128
#define LCH  64
#define NCHK 32
#define NBH  32
#define SEQ  2048
#define NCHUNKS 1024
#define SCALE 0.08838834764831845f

typedef unsigned short u16;
typedef unsigned int   u32;
typedef __attribute__((ext_vector_type(8))) short bf16x8;
typedef __attribute__((ext_vector_type(4))) float f32x4;

__device__ __forceinline__ u16 f2bf(float f) {
    u32 u; __builtin_memcpy(&u, &f, 4);
    u32 r = u + 0x7fffu + ((u >> 16) & 1u);   // RNE
    return (u16)(r >> 16);
}
__device__ __forceinline__ u32 rne_bits(float x) {
    u32 u; __builtin_memcpy(&u, &x, 4);
    return u + 0x7fffu + ((u >> 16) & 1u);
}
__device__ __forceinline__ u32 pk_rne(float a, float b) {
    return (rne_bits(a) >> 16) | (rne_bits(b) & 0xffff0000u);
}
// split pair of f32 into hi (truncated bf16 pair) + lo (residual RNE bf16 pair)
__device__ __forceinline__ void split2(float a, float b, u32& hw, u32& lw) {
    u32 u0, u1;
    __builtin_memcpy(&u0, &a, 4);
    __builtin_memcpy(&u1, &b, 4);
    const u32 h0 = u0 & 0xffff0000u, h1 = u1 & 0xffff0000u;
    hw = (h0 >> 16) | h1;
    float f0, f1;
    __builtin_memcpy(&f0, &h0, 4);
    __builtin_memcpy(&f1, &h1, 4);
    lw = pk_rne(a - f0, b - f1);
}
__device__ __forceinline__ void split8(const float* s, uint4& hi, uint4& lo) {
    u32 hw[4], lw[4];
    #pragma unroll
    for (int m = 0; m < 4; ++m) split2(s[2*m], s[2*m+1], hw[m], lw[m]);
    hi.x = hw[0]; hi.y = hw[1]; hi.z = hw[2]; hi.w = hw[3];
    lo.x = lw[0]; lo.y = lw[1]; lo.z = lw[2]; lo.w = lw[3];
}
// packed split element: low16 = bf16-hi(x), high16 = bf16-lo(residual)
__device__ __forceinline__ u32 packsplit(float x) {
    u32 u; __builtin_memcpy(&u, &x, 4);
    const u32 hi = u & 0xffff0000u;
    float fh; __builtin_memcpy(&fh, &hi, 4);
    const u32 lo = rne_bits(x - fh) & 0xffff0000u;
    return (hi >> 16) | lo;
}
// 8 packed elems (2 uint4) -> hi-frag word4 + lo-frag word4
__device__ __forceinline__ void unpack2(const uint4 p0, const uint4 p1, uint4& hi, uint4& lo) {
    hi.x = (p0.x & 0xffffu) | (p0.y << 16);
    lo.x = (p0.x >> 16)     | (p0.y & 0xffff0000u);
    hi.y = (p0.z & 0xffffu) | (p0.w << 16);
    lo.y = (p0.z >> 16)     | (p0.w & 0xffff0000u);
    hi.z = (p1.x & 0xffffu) | (p1.y << 16);
    lo.z = (p1.x >> 16)     | (p1.y & 0xffff0000u);
    hi.w = (p1.z & 0xffffu) | (p1.w << 16);
    lo.w = (p1.z >> 16)     | (p1.w & 0xffff0000u);
}
__device__ __forceinline__ f32x4 mfma_bf(uint4 a, uint4 b, f32x4 c) {
    union { uint4 u; bf16x8 v; } A, B;
    A.u = a; B.u = b;
    return __builtin_amdgcn_mfma_f32_16x16x32_bf16(A.v, B.v, c, 0, 0, 0);
}

// ---------- kept for symbol compatibility (not launched) ----------
extern "C" __global__ __launch_bounds__(256)
void KDABlock_4475355922517_kernel(float* out, int n, float val)
{
    int stride = gridDim.x * blockDim.x;
    for (int i = blockIdx.x * blockDim.x + threadIdx.x; i < n; i += stride)
        out[i] = val;
}

// ---------- Phase A1 v2: MFMA for kk/qk/G; solve kept; same ws formats ----------
// LDS union U (52,224 B):
//   gcum phase : float gbuf[64][130]
//   matmul     : u32 sOp[3][64][68]   (0=khi, 1=klo, 2=qlo; packed hi|lo<<16)
//   solve/G    : float tkk[64][68] | tT[64][68] | sqk[64][68]
extern "C" __global__ __launch_bounds__(512)
void kda_phaseA1(const float* gq, const float* gk, const float* gg, const float* gbeta,
                 u16* wkhi, u16* wqn, float* wT, float* wG, float* wegt, float* wegcm)
{
    __shared__ u32 U[13056];
    __shared__ float sbeta[64];
    float* fU = (float*)U;

    const int chunk = blockIdx.x;
    const int bh = chunk >> 5, tt = chunk & 31;
    const int tid = threadIdx.x;
    const int base = bh * (SEQ * CDIM) + tt * (LCH * CDIM);
    const int row = tid >> 3, part = tid & 7;
    const int j0 = part * 8;
    const int w = tid >> 6, l = tid & 63;
    const int ln = l & 15, lh = l >> 4;
    const int mt = w & 3;
    const int nt0 = (w >> 2) * 2, nt1 = nt0 + 1;

    // ---- gcum: segmented cumsum over 64 rows per column (gbuf stride 130) ----
    {
        const int col = tid & 127, seg = tid >> 7;
        float acc = 0.f;
        for (int r = 0; r < 16; ++r) {
            const int i = seg * 16 + r;
            acc += gg[base + i * CDIM + col];
            fU[i * 130 + col] = acc;
        }
        __syncthreads();
        float off = 0.f;
        for (int s = 0; s < seg; ++s) off += fU[(s * 16 + 15) * 130 + col];
        __syncthreads();
        if (seg) for (int r = 0; r < 16; ++r) fU[(seg * 16 + r) * 130 + col] += off;
        if (tid < 64) sbeta[tid] = gbeta[bh * SEQ + tt * LCH + tid];
    }
    __syncthreads();

    // ---- gcum -> regs; egt; egcm ----
    float gc[16];
    #pragma unroll
    for (int c = 0; c < 16; ++c) gc[c] = fU[row * 130 + part * 16 + c];
    if (tid < 128) wegt[chunk * CDIM + tid] = __expf(fU[63 * 130 + tid]);
    float egr;
    {
        float s = 0.f;
        #pragma unroll
        for (int c = 0; c < 16; ++c) s += gc[c];
        s += __shfl_xor(s, 1); s += __shfl_xor(s, 2); s += __shfl_xor(s, 4);
        egr = __expf(s * (1.f / 128.f));
        if (part == 0) wegcm[chunk * LCH + row] = egr;
    }

    // ---- k: normalize -> khi/klo regs; khi -> ws (bf16 row-major) ----
    float khi[16], klo[16];
    {
        float ss = 0.f;
        const float* kp = gk + base + row * CDIM + part * 16;
        #pragma unroll
        for (int c = 0; c < 16; ++c) { khi[c] = kp[c]; ss += khi[c] * khi[c]; }
        ss += __shfl_xor(ss, 1); ss += __shfl_xor(ss, 2); ss += __shfl_xor(ss, 4);
        const float inv = 1.f / (sqrtf(ss) + 1e-6f);
        #pragma unroll
        for (int c = 0; c < 16; ++c) {
            const float kn = khi[c] * inv;
            khi[c] = kn * __expf(gc[c]);
            klo[c] = kn * __expf(-gc[c]);
            wkhi[chunk * 8192 + row * CDIM + part * 16 + c] = f2bf(khi[c]);
        }
    }

    // ---- q: normalize -> qlo regs; Qn -> ws (bf16 row-major) ----
    float qlo[16];
    {
        float ss = 0.f;
        const float* qp = gq + base + row * CDIM + part * 16;
        #pragma unroll
        for (int c = 0; c < 16; ++c) { qlo[c] = qp[c]; ss += qlo[c] * qlo[c]; }
        ss += __shfl_xor(ss, 1); ss += __shfl_xor(ss, 2); ss += __shfl_xor(ss, 4);
        const float inv = 1.f / (sqrtf(ss) + 1e-6f);
        const float qs = SCALE * egr * inv;
        #pragma unroll
        for (int c = 0; c < 16; ++c) {
            wqn[chunk * 8192 + row * CDIM + part * 16 + c] = f2bf(qlo[c] * qs);
            qlo[c] = qlo[c] * inv * __expf(-gc[c]);
        }
    }
    __syncthreads();   // gcum region dead

    // ---- MFMA: kk = klo@khi^T, qk = qlo@khi^T over two K-halves ----
    f32x4 aKK0 = {0.f,0.f,0.f,0.f}, aKK1 = {0.f,0.f,0.f,0.f};
    f32x4 aQK0 = {0.f,0.f,0.f,0.f}, aQK1 = {0.f,0.f,0.f,0.f};
    #pragma unroll
    for (int h = 0; h < 2; ++h) {
        // stage half h: cols 64h..64h+63 (threads with part>>2 == h)
        if ((part >> 2) == h) {
            const int cc = (part & 3) * 16;
            uint4 v;
            #pragma unroll
            for (int g4 = 0; g4 < 4; ++g4) {
                v.x = packsplit(khi[4*g4+0]); v.y = packsplit(khi[4*g4+1]);
                v.z = packsplit(khi[4*g4+2]); v.w = packsplit(khi[4*g4+3]);
                *(uint4*)&U[0*4352 + row*68 + cc + 4*g4] = v;
                v.x = packsplit(klo[4*g4+0]); v.y = packsplit(klo[4*g4+1]);
                v.z = packsplit(klo[4*g4+2]); v.w = packsplit(klo[4*g4+3]);
                *(uint4*)&U[1*4352 + row*68 + cc + 4*g4] = v;
                v.x = packsplit(qlo[4*g4+0]); v.y = packsplit(qlo[4*g4+1]);
                v.z = packsplit(qlo[4*g4+2]); v.w = packsplit(qlo[4*g4+3]);
                *(uint4*)&U[2*4352 + row*68 + cc + 4*g4] = v;
            }
        }
        __syncthreads();
        #pragma unroll
        for (int ks2 = 0; ks2 < 2; ++ks2) {
            const int cb = 32*ks2 + 8*lh;
            uint4 p0, p1, aH, aL, qH, qL, bH, bL;
            p0 = *(const uint4*)&U[1*4352 + (16*mt+ln)*68 + cb];
            p1 = *(const uint4*)&U[1*4352 + (16*mt+ln)*68 + cb + 4];
            unpack2(p0, p1, aH, aL);
            p0 = *(const uint4*)&U[2*4352 + (16*mt+ln)*68 + cb];
            p1 = *(const uint4*)&U[2*4352 + (16*mt+ln)*68 + cb + 4];
            unpack2(p0, p1, qH, qL);
            p0 = *(const uint4*)&U[0*4352 + (16*nt0+ln)*68 + cb];
            p1 = *(const uint4*)&U[0*4352 + (16*nt0+ln)*68 + cb + 4];
            unpack2(p0, p1, bH, bL);
            aKK0 = mfma_bf(aH, bH, aKK0); aKK0 = mfma_bf(aH, bL, aKK0);
            aKK0 = mfma_bf(aL, bH, aKK0);
            aQK0 = mfma_bf(qH, bH, aQK0); aQK0 = mfma_bf(qH, bL, aQK0);
            aQK0 = mfma_bf(qL, bH, aQK0);
            p0 = *(const uint4*)&U[0*4352 + (16*nt1+ln)*68 + cb];
            p1 = *(const uint4*)&U[0*4352 + (16*nt1+ln)*68 + cb + 4];
            unpack2(p0, p1, bH, bL);
            aKK1 = mfma_bf(aH, bH, aKK1); aKK1 = mfma_bf(aH, bL, aKK1);
            aKK1 = mfma_bf(aL, bH, aKK1);
            aQK1 = mfma_bf(qH, bH, aQK1); aQK1 = mfma_bf(qH, bL, aQK1);
            aQK1 = mfma_bf(qL, bH, aQK1);
        }
        __syncthreads();   // half consumed before restage / C-write
    }

    // ---- C-frags -> tkk (fU[0..]) and masked qk -> sqk (fU[8704..]) ----
    #pragma unroll
    for (int r = 0; r < 4; ++r) {
        const int gr = 16*mt + 4*lh + r;
        const int gc0 = 16*nt0 + ln, gc1 = 16*nt1 + ln;
        fU[gr*68 + gc0] = aKK0[r];
        fU[gr*68 + gc1] = aKK1[r];
        fU[8704 + gr*68 + gc0] = (gc0 <= gr) ? aQK0[r] * SCALE : 0.f;
        fU[8704 + gr*68 + gc1] = (gc1 <= gr) ? aQK1[r] * SCALE : 0.f;
    }
    __syncthreads();

    // ---- T solve: (I + beta_i*strict_lower(kk)) T = diag(beta); lane j owns col j ----
    if (tid < 64) {
        const int j = tid;
        for (int i = 0; i < LCH; ++i) {
            float s0 = 0.f, s1 = 0.f, s2 = 0.f, s3 = 0.f;
            int m = 0;
            for (; m + 4 <= i; m += 4) {
                const float4 k4 = *(const float4*)&fU[i*68 + m];
                s0 += k4.x * fU[4352 + (m+0)*68 + j];
                s1 += k4.y * fU[4352 + (m+1)*68 + j];
                s2 += k4.z * fU[4352 + (m+2)*68 + j];
                s3 += k4.w * fU[4352 + (m+3)*68 + j];
            }
            for (; m < i; ++m) s0 += fU[i*68 + m] * fU[4352 + m*68 + j];
            fU[4352 + i*68 + j] = sbeta[i] * (((j == i) ? 1.f : 0.f) - ((s0+s1)+(s2+s3)));
        }
    }
    __syncthreads();

    // ---- T -> ws (f32 row-major) ----
    #pragma unroll
    for (int d = 0; d < 8; ++d)
        wT[chunk * 4096 + row * 64 + j0 + d] = fU[4352 + row*68 + j0 + d];

    // ---- G = qk_masked @ T via MFMA (A = sqk split, B = T split) ----
    {
        f32x4 aG0 = {0.f,0.f,0.f,0.f}, aG1 = {0.f,0.f,0.f,0.f};
        #pragma unroll
        for (int ks2 = 0; ks2 < 2; ++ks2) {
            const int cb = 32*ks2 + 8*lh;
            float av[8];
            *(float4*)&av[0] = *(const float4*)&fU[8704 + (16*mt+ln)*68 + cb];
            *(float4*)&av[4] = *(const float4*)&fU[8704 + (16*mt+ln)*68 + cb + 4];
            uint4 ah, al; split8(av, ah, al);
            float bv[8];
            uint4 bh, bl;
            #pragma unroll
            for (int j = 0; j < 8; ++j) bv[j] = fU[4352 + (cb+j)*68 + 16*nt0+ln];
            split8(bv, bh, bl);
            aG0 = mfma_bf(ah, bh, aG0); aG0 = mfma_bf(ah, bl, aG0);
            aG0 = mfma_bf(al, bh, aG0);
            #pragma unroll
            for (int j = 0; j < 8; ++j) bv[j] = fU[4352 + (cb+j)*68 + 16*nt1+ln];
            split8(bv, bh, bl);
            aG1 = mfma_bf(ah, bh, aG1); aG1 = mfma_bf(ah, bl, aG1);
            aG1 = mfma_bf(al, bh, aG1);
        }
        #pragma unroll
        for (int r = 0; r < 4; ++r) {
            const int gr = 16*mt + 4*lh + r;
            wG[chunk * 4096 + gr * 64 + 16*nt0 + ln] = aG0[r];
            wG[chunk * 4096 + gr * 64 + 16*nt1 + ln] = aG1[r];
        }
    }
}

// ---------- Phase A2: repack row-major -> MFMA fragment order (round-11 verbatim) ----------
extern "C" __global__ __launch_bounds__(256)
void kda_phaseA2(u16* slot1, u16* slot2, float* wTf, float* wGf,
                 u16* wTAl, u16* wGAl, int useLo)
{
    const int chunk = blockIdx.x;
    const int tid = threadIdx.x;
    const size_t cb16 = (size_t)chunk * 8192;
    const size_t cbf  = (size_t)chunk * 4096;

    u16* slot3u = (u16*)wTf;
    u16* slot4u = (u16*)wGf;

    // ---- load phase ----
    uint4 ka[4], qa[4];
    #pragma unroll
    for (int i = 0; i < 4; ++i) {
        const int fw = tid + 256 * i;
        const int mt = fw >> 8, ks = (fw >> 6) & 3, l = fw & 63;
        const size_t src = cb16 + (size_t)(16 * mt + (l & 15)) * 128 + 32 * ks + 8 * (l >> 4);
        ka[i] = *(const uint4*)(slot1 + src);
        qa[i] = *(const uint4*)(slot2 + src);
    }
    u32 kt[4][4];
    #pragma unroll
    for (int i = 0; i < 4; ++i) {
        const int fw = tid + 256 * i;
        const int mt = fw >> 7, ks = (fw >> 6) & 1, l = fw & 63;
        const int col = 16 * mt + (l & 15);
        const int rb = 32 * ks + 8 * (l >> 4);
        #pragma unroll
        for (int p = 0; p < 4; ++p) {
            const u16 a = slot1[cb16 + (size_t)(rb + 2 * p) * 128 + col];
            const u16 b = slot1[cb16 + (size_t)(rb + 2 * p + 1) * 128 + col];
            kt[i][p] = (u32)a | ((u32)b << 16);
        }
    }
    float tv[2][8], gv2[2][8];
    #pragma unroll
    for (int i = 0; i < 2; ++i) {
        const int fw = tid + 256 * i;
        const int mt = fw >> 7, ks = (fw >> 6) & 1, l = fw & 63;
        const size_t src = cbf + (size_t)(16 * mt + (l & 15)) * 64 + 32 * ks + 8 * (l >> 4);
        *(float4*)&tv[i][0]  = *(const float4*)(wTf + src);
        *(float4*)&tv[i][4]  = *(const float4*)(wTf + src + 4);
        *(float4*)&gv2[i][0] = *(const float4*)(wGf + src);
        *(float4*)&gv2[i][4] = *(const float4*)(wGf + src + 4);
    }
    __syncthreads();

    // ---- store phase ----
    #pragma unroll
    for (int i = 0; i < 4; ++i) {
        const int fw = tid + 256 * i;
        uint4 kv = ka[i];
        kv.x ^= 0x80008000u; kv.y ^= 0x80008000u;
        kv.z ^= 0x80008000u; kv.w ^= 0x80008000u;
        *(uint4*)(slot1 + cb16 + (size_t)fw * 8) = kv;
        *(uint4*)(slot2 + cb16 + (size_t)fw * 8) = qa[i];
        uint4 kw;
        kw.x = kt[i][0]; kw.y = kt[i][1]; kw.z = kt[i][2]; kw.w = kt[i][3];
        *(uint4*)(slot4u + cb16 + (size_t)fw * 8) = kw;
    }
    #pragma unroll
    for (int i = 0; i < 2; ++i) {
        const int fw = tid + 256 * i;
        uint4 th, tl, gh, gl;
        split8(tv[i],  th, tl);
        split8(gv2[i], gh, gl);
        *(uint4*)(slot3u + cb16 + (size_t)fw * 8) = th;
        *(uint4*)(slot3u + cb16 + 4096 + (size_t)fw * 8) = gh;
        if (useLo) {
            *(uint4*)(wTAl + cbf + (size_t)fw * 8) = tl;
            *(uint4*)(wGAl + cbf + (size_t)fw * 8) = gl;
        }
    }
}

// ---------- Phase B: MFMA scan (round-11 verbatim) ----------
extern "C" __global__ __launch_bounds__(256)
void kda_phaseB(const u16* wKA, const u16* wQA, const u16* wKTA,
                const u16* wTGh, const u16* wTAl, const u16* wGAl,
                const float* wegt, const float* wegcm,
                const float* gv, float* gout, int useLo)
{
    __shared__ float sS[128 * 17];
    __shared__ float sX[64 * 17];
    __shared__ float sC[64 * 17];
    __shared__ float sEt[128];
    __shared__ float sEm[64];

    const int bh = blockIdx.x >> 3;
    const int c0 = (blockIdx.x & 7) * 16;
    const int tid = threadIdx.x;
    const int w = tid >> 6;
    const int l = tid & 63;
    const int ln = l & 15;
    const int lh = l >> 4;

    for (int e = tid; e < 128 * 17; e += 256) sS[e] = 0.f;

    float* outO = gout + (size_t)bh * (SEQ * CDIM);
    float* outS = gout + (size_t)NBH * SEQ * CDIM + (size_t)bh * (CDIM * CDIM);

    for (int t = 0; t < NCHK; ++t) {
        const size_t ch = (size_t)(bh * NCHK + t);

        uint4 kf[4], qf[4];
        const u16* pK = wKA + ch * 8192 + (size_t)w * 2048 + (size_t)l * 8;
        const u16* pQ = wQA + ch * 8192 + (size_t)w * 2048 + (size_t)l * 8;
        #pragma unroll
        for (int ks = 0; ks < 4; ++ks) {
            kf[ks] = *(const uint4*)(pK + ks * 512);
            qf[ks] = *(const uint4*)(pQ + ks * 512);
        }
        uint4 tfh[2], gfh[2], tfl[2], gfl[2];
        const size_t tb = ch * 8192 + (size_t)w * 1024 + (size_t)l * 8;
        #pragma unroll
        for (int ks = 0; ks < 2; ++ks) {
            tfh[ks] = *(const uint4*)(wTGh + tb + ks * 512);
            gfh[ks] = *(const uint4*)(wTGh + tb + 4096 + ks * 512);
        }
        if (useLo) {
            const size_t tbl = ch * 4096 + (size_t)w * 1024 + (size_t)l * 8;
            #pragma unroll
            for (int ks = 0; ks < 2; ++ks) {
                tfl[ks] = *(const uint4*)(wTAl + tbl + ks * 512);
                gfl[ks] = *(const uint4*)(wGAl + tbl + ks * 512);
            }
        }
        uint4 ktf[2][2];
        #pragma unroll
        for (int m2 = 0; m2 < 2; ++m2)
            #pragma unroll
            for (int ks = 0; ks < 2; ++ks)
                ktf[m2][ks] = *(const uint4*)(wKTA + ch * 8192
                                + (size_t)((2*w + m2) * 2 + ks) * 512 + (size_t)l * 8);
        float vg[4];
        #pragma unroll
        for (int r = 0; r < 4; ++r) {
            const int row = 16 * w + 4 * lh + r;
            vg[r] = gv[(size_t)bh * SEQ * CDIM + (size_t)(t * LCH + row) * CDIM + c0 + ln];
        }
        if (tid < 128) sEt[tid] = wegt[ch * CDIM + tid];
        else if (tid < 192) sEm[tid - 128] = wegcm[ch * LCH + (tid - 128)];
        __syncthreads();

        f32x4 accX, accO;
        #pragma unroll
        for (int r = 0; r < 4; ++r) {
            accX[r] = vg[r] * sEm[16 * w + 4 * lh + r];
            accO[r] = 0.f;
        }

        #pragma unroll
        for (int ks = 0; ks < 4; ++ks) {
            float sv[8];
            const int kb = 32 * ks + 8 * lh;
            #pragma unroll
            for (int j = 0; j < 8; ++j) sv[j] = sS[(kb + j) * 17 + ln];
            uint4 hi, lo; split8(sv, hi, lo);
            accX = mfma_bf(kf[ks], hi, accX);
            accX = mfma_bf(kf[ks], lo, accX);
            accO = mfma_bf(qf[ks], hi, accO);
            accO = mfma_bf(qf[ks], lo, accO);
        }
        #pragma unroll
        for (int r = 0; r < 4; ++r) sX[(16 * w + 4 * lh + r) * 17 + ln] = accX[r];
        __syncthreads();

        f32x4 accC = {0.f, 0.f, 0.f, 0.f};
        #pragma unroll
        for (int ks = 0; ks < 2; ++ks) {
            float xv[8];
            const int kb = 32 * ks + 8 * lh;
            #pragma unroll
            for (int j = 0; j < 8; ++j) xv[j] = sX[(kb + j) * 17 + ln];
            uint4 xh, xl; split8(xv, xh, xl);
            accC = mfma_bf(tfh[ks], xh, accC);
            accC = mfma_bf(tfh[ks], xl, accC);
            accO = mfma_bf(gfh[ks], xh, accO);
            accO = mfma_bf(gfh[ks], xl, accO);
            if (useLo) {
                accC = mfma_bf(tfl[ks], xh, accC);
                accO = mfma_bf(gfl[ks], xh, accO);
            }
        }
        #pragma unroll
        for (int r = 0; r < 4; ++r) {
            const int row = 16 * w + 4 * lh + r;
            outO[(size_t)(t * LCH + row) * CDIM + c0 + ln] = accO[r];
            sC[row * 17 + ln] = accC[r];
        }
        __syncthreads();

        uint4 csh[2], csl[2];
        #pragma unroll
        for (int ks = 0; ks < 2; ++ks) {
            float cv[8];
            const int kb = 32 * ks + 8 * lh;
            #pragma unroll
            for (int j = 0; j < 8; ++j) cv[j] = sC[(kb + j) * 17 + ln];
            split8(cv, csh[ks], csl[ks]);
        }
        #pragma unroll
        for (int m2 = 0; m2 < 2; ++m2) {
            const int mt = 2 * w + m2;
            f32x4 accS;
            #pragma unroll
            for (int r = 0; r < 4; ++r) {
                const int row = 16 * mt + 4 * lh + r;
                accS[r] = sEt[row] * sS[row * 17 + ln];
            }
            #pragma unroll
            for (int ks = 0; ks < 2; ++ks) {
                accS = mfma_bf(ktf[m2][ks], csh[ks], accS);
                accS = mfma_bf(ktf[m2][ks], csl[ks], accS);
            }
            #pragma unroll
            for (int r = 0; r < 4; ++r) {
                const int row = 16 * mt + 4 * lh + r;
                sS[row * 17 + ln] = accS[r];
            }
        }
        __syncthreads();
    }

    {
        const int col = tid & 15, rb = (tid >> 4) * 8;
        #pragma unroll
        for (int r = 0; r < 8; ++r)
            outS[(size_t)(rb + r) * CDIM + c0 + col] = sS[(rb + r) * 17 + col];
    }
}

extern "C" __attribute__((visibility("default")))
void kernel_launch(void* const* d_in, const int* in_sizes, int n_in,
                   void* d_out, int out_size, void* d_ws, size_t ws_size,
                   hipStream_t stream)
{
    (void)in_sizes; (void)n_in; (void)out_size;

    const size_t NEED1 = (size_t)NCHUNKS * (8192*2*2 + 4096*4*2)
                       + (size_t)NCHUNKS * (CDIM + LCH) * 4;
    const size_t NEED2 = NEED1 + (size_t)NCHUNKS * 4096 * 2 * 2;
    if (d_ws == 0 || ws_size < NEED1) return;
    const int useLo = (ws_size >= NEED2) ? 1 : 0;

    const float* q    = (const float*)d_in[0];
    const float* k    = (const float*)d_in[1];
    const float* v    = (const float*)d_in[2];
    const float* g    = (const float*)d_in[3];
    const float* beta = (const float*)d_in[4];
    float* out = (float*)d_out;

    u16* slot1   = (u16*)d_ws;
    u16* slot2   = slot1 + (size_t)NCHUNKS * 8192;
    float* wT    = (float*)(slot2 + (size_t)NCHUNKS * 8192);
    float* wG    = wT + (size_t)NCHUNKS * 4096;
    float* wegt  = wG + (size_t)NCHUNKS * 4096;
    float* wegcm = wegt + (size_t)NCHUNKS * CDIM;
    u16* wTAl    = (u16*)(wegcm + (size_t)NCHUNKS * LCH);
    u16* wGAl    = wTAl + (size_t)NCHUNKS * 4096;
    if (!useLo) { wTAl = slot1; wGAl = slot1; }

    kda_phaseA1<<<NCHUNKS, 512, 0, stream>>>(q, k, g, beta, slot1, slot2,
                                             wT, wG, wegt, wegcm);
    kda_phaseA2<<<NCHUNKS, 256, 0, stream>>>(slot1, slot2, wT, wG,
                                             wTAl, wGAl, useLo);
    kda_phaseB<<<NBH * 8, 256, 0, stream>>>(slot1, slot2, (u16*)wG, (u16*)wT,
                                            wTAl, wGAl, wegt, wegcm, v, out, useLo);
}